// Round 9
// baseline (1291.942 us; speedup 1.0000x reference)
//
#include <hip/hip_runtime.h>

// ---------------------------------------------------------------------------
// mLSTM block, MI355X. B=2,S=2048,D=1024,NH=8,DH=128.
// v8: quarter-channel attn (2048 blocks), K direct from L2, <=64 VGPR target,
//     ~14KB LDS -> 8 blocks/CU. Scalar-fp32 PV (proven numerics).
// ---------------------------------------------------------------------------

typedef __bf16 bf16x8 __attribute__((ext_vector_type(8)));
typedef float f32x4 __attribute__((ext_vector_type(4)));
typedef float f32x2 __attribute__((ext_vector_type(2)));
typedef unsigned short us8 __attribute__((ext_vector_type(8)));
typedef unsigned short us4 __attribute__((ext_vector_type(4)));
typedef unsigned short us2 __attribute__((ext_vector_type(2)));

__device__ __forceinline__ unsigned short f2bf(float f) {
    unsigned int u = __builtin_bit_cast(unsigned int, f);
    unsigned int r = u + 0x7fffu + ((u >> 16) & 1u);
    return (unsigned short)(r >> 16);
}
__device__ __forceinline__ float bf2f(unsigned short h) {
    unsigned int u = ((unsigned int)h) << 16;
    return __builtin_bit_cast(float, u);
}
__device__ __forceinline__ f32x4 mfma16(bf16x8 a, bf16x8 b, f32x4 c) {
    return __builtin_amdgcn_mfma_f32_16x16x32_bf16(a, b, c, 0, 0, 0);
}

// ---------------- K0 ----------------
__global__ __launch_bounds__(256) void k_split_bf16(const float* __restrict__ in,
                                                    unsigned short* __restrict__ hi,
                                                    unsigned short* __restrict__ lo, int n) {
    int i = blockIdx.x * 256 + threadIdx.x;
    if (i < n) {
        float f = in[i];
        unsigned short h = f2bf(f);
        hi[i] = h;
        lo[i] = f2bf(f - bf2f(h));
    }
}

__global__ __launch_bounds__(256) void build_wcat(const float* __restrict__ Wq,
                                                  const float* __restrict__ Wk,
                                                  const float* __restrict__ Wv,
                                                  const float* __restrict__ Wog,
                                                  unsigned short* __restrict__ wh,
                                                  unsigned short* __restrict__ wl) {
    int idx = blockIdx.x * 256 + threadIdx.x;
    if (idx >= 2304 * 1024) return;
    int row = idx >> 10, col = idx & 1023;
    float v;
    if (row < 1024)      v = Wq[(size_t)row * 1024 + col] * 0.08838834764831845f;
    else if (row < 1152) v = Wk[(size_t)(row - 1024) * 1024 + col];
    else if (row < 1280) v = Wv[(size_t)(row - 1152) * 1024 + col];
    else                 v = Wog[(size_t)(row - 1280) * 1024 + col];
    unsigned short h = f2bf(v);
    wh[idx] = h;
    wl[idx] = f2bf(v - bf2f(h));
}

// ---------------- K1: gates ----------------
__global__ __launch_bounds__(256) void gates_kernel(const float* __restrict__ x,
                                                    const float* __restrict__ Wi,
                                                    const float* __restrict__ bi,
                                                    const float* __restrict__ Wf,
                                                    const float* __restrict__ bfb,
                                                    float* __restrict__ ipre,
                                                    float* __restrict__ lgf) {
    int bs = blockIdx.x;
    int b = bs >> 11, s = bs & 2047;
    const float* xr = x + (size_t)bs * 1024;
    int lane = threadIdx.x & 63, w = threadIdx.x >> 6;
    const float* W = (w < 2) ? Wi : Wf;
    int h0 = (w & 1) * 4;
    float dot0 = 0.f, dot1 = 0.f, dot2 = 0.f, dot3 = 0.f;
    for (int i = lane; i < 1024; i += 64) {
        float xv = xr[i];
        dot0 += xv * W[(size_t)(h0 + 0) * 1024 + i];
        dot1 += xv * W[(size_t)(h0 + 1) * 1024 + i];
        dot2 += xv * W[(size_t)(h0 + 2) * 1024 + i];
        dot3 += xv * W[(size_t)(h0 + 3) * 1024 + i];
    }
#pragma unroll
    for (int o = 32; o; o >>= 1) {
        dot0 += __shfl_xor(dot0, o);
        dot1 += __shfl_xor(dot1, o);
        dot2 += __shfl_xor(dot2, o);
        dot3 += __shfl_xor(dot3, o);
    }
    if (lane == 0) {
        float d[4] = {dot0, dot1, dot2, dot3};
#pragma unroll
        for (int j = 0; j < 4; j++) {
            int hh = h0 + j;
            if (w < 2) {
                float z = d[j] + bi[hh];
                z = 15.f * tanhf(z * (1.f / 15.f));
                ipre[((size_t)b * 8 + hh) * 2048 + s] = z;
            } else {
                float z = d[j] + bfb[hh];
                z = 15.f * tanhf(z * (1.f / 15.f));
                lgf[((size_t)b * 8 + hh) * 2048 + s] = fminf(z, 0.f) - log1pf(expf(-fabsf(z)));
            }
        }
    }
}

// ---------------- K2: scan ----------------
__global__ void scan_kernel(const float* __restrict__ ipre, const float* __restrict__ lgf,
                            float* __restrict__ csum, float* __restrict__ aarr,
                            float* __restrict__ marr) {
    int bh = blockIdx.x;
    int lane = threadIdx.x;
    const float* lf = lgf + (size_t)bh * 2048;
    const float* ip = ipre + (size_t)bh * 2048;
    float* cs = csum + (size_t)bh * 2048;
    float* aa = aarr + (size_t)bh * 2048;
    float* mm = marr + (size_t)bh * 2048;
    float carry = 0.f;
    float carrym = -1e30f;
    for (int c = 0; c < 32; c++) {
        float v = lf[c * 64 + lane];
#pragma unroll
        for (int o = 1; o < 64; o <<= 1) {
            float t = __shfl_up(v, o);
            if (lane >= o) v += t;
        }
        float cval = carry + v;
        cs[c * 64 + lane] = cval;
        float a = ip[c * 64 + lane] - cval;
        aa[c * 64 + lane] = a;
        float mv = a;
#pragma unroll
        for (int o = 1; o < 64; o <<= 1) {
            float t = __shfl_up(mv, o);
            if (lane >= o) mv = fmaxf(mv, t);
        }
        float mval = fmaxf(carrym, mv);
        mm[c * 64 + lane] = mval;
        carry = __shfl(cval, 63);
        carrym = __shfl(mval, 63);
    }
}

// ---- K3/K6: 3-product GEMM, 128x128 tile ----
__global__ __launch_bounds__(256) void gemm_bt3(const unsigned short* __restrict__ Ah,
                                                const unsigned short* __restrict__ Al,
                                                const unsigned short* __restrict__ Bh,
                                                const unsigned short* __restrict__ Bl,
                                                void* __restrict__ Cp,
                                                unsigned short* __restrict__ Clo,
                                                int K, int ldc, int c_bf16) {
    __shared__ __attribute__((aligned(16))) unsigned short Ash[128 * 40];
    __shared__ __attribute__((aligned(16))) unsigned short Asl[128 * 40];
    __shared__ __attribute__((aligned(16))) unsigned short Bsh[128 * 40];
    __shared__ __attribute__((aligned(16))) unsigned short Bsl[128 * 40];
    const int tid = threadIdx.x;
    const int lane = tid & 63, wv = tid >> 6;
    const int wr = wv >> 1, wc = wv & 1;
    const int fr = lane & 15, fg = lane >> 4;
    const int srow = tid >> 1, scol = (tid & 1) * 16;
    const size_t aoff = (size_t)(blockIdx.x * 128 + srow) * K + scol;
    const size_t boff = (size_t)(blockIdx.y * 128 + srow) * K + scol;
    f32x4 acc[4][4] = {};
    for (int kt = 0; kt < K; kt += 32) {
        us8 avh0 = *(const us8*)(Ah + aoff + kt);
        us8 avh1 = *(const us8*)(Ah + aoff + kt + 8);
        us8 avl0 = *(const us8*)(Al + aoff + kt);
        us8 avl1 = *(const us8*)(Al + aoff + kt + 8);
        us8 bvh0 = *(const us8*)(Bh + boff + kt);
        us8 bvh1 = *(const us8*)(Bh + boff + kt + 8);
        us8 bvl0 = *(const us8*)(Bl + boff + kt);
        us8 bvl1 = *(const us8*)(Bl + boff + kt + 8);
        __syncthreads();
        *(us8*)&Ash[srow * 40 + scol] = avh0;
        *(us8*)&Ash[srow * 40 + scol + 8] = avh1;
        *(us8*)&Asl[srow * 40 + scol] = avl0;
        *(us8*)&Asl[srow * 40 + scol + 8] = avl1;
        *(us8*)&Bsh[srow * 40 + scol] = bvh0;
        *(us8*)&Bsh[srow * 40 + scol + 8] = bvh1;
        *(us8*)&Bsl[srow * 40 + scol] = bvl0;
        *(us8*)&Bsl[srow * 40 + scol + 8] = bvl1;
        __syncthreads();
        bf16x8 bfh[4], bfl[4];
#pragma unroll
        for (int j = 0; j < 4; j++) {
            bfh[j] = __builtin_bit_cast(bf16x8, *(const us8*)&Bsh[(64 * wc + 16 * j + fr) * 40 + fg * 8]);
            bfl[j] = __builtin_bit_cast(bf16x8, *(const us8*)&Bsl[(64 * wc + 16 * j + fr) * 40 + fg * 8]);
        }
        __builtin_amdgcn_s_setprio(1);
#pragma unroll
        for (int i = 0; i < 4; i++) {
            bf16x8 afh = __builtin_bit_cast(bf16x8, *(const us8*)&Ash[(64 * wr + 16 * i + fr) * 40 + fg * 8]);
            bf16x8 afl = __builtin_bit_cast(bf16x8, *(const us8*)&Asl[(64 * wr + 16 * i + fr) * 40 + fg * 8]);
#pragma unroll
            for (int j = 0; j < 4; j++) {
                acc[i][j] = mfma16(afh, bfh[j], acc[i][j]);
                acc[i][j] = mfma16(afh, bfl[j], acc[i][j]);
                acc[i][j] = mfma16(afl, bfh[j], acc[i][j]);
            }
        }
        __builtin_amdgcn_s_setprio(0);
    }
#pragma unroll
    for (int i = 0; i < 4; i++)
#pragma unroll
        for (int j = 0; j < 4; j++)
#pragma unroll
            for (int e = 0; e < 4; e++) {
                int r = blockIdx.x * 128 + 64 * wr + 16 * i + fg * 4 + e;
                int c = blockIdx.y * 128 + 64 * wc + 16 * j + fr;
                float v = acc[i][j][e];
                if (c_bf16) {
                    unsigned short h = f2bf(v);
                    ((unsigned short*)Cp)[(size_t)r * ldc + c] = h;
                    Clo[(size_t)r * ldc + c] = f2bf(v - bf2f(h));
                } else {
                    ((float*)Cp)[(size_t)r * ldc + c] = v;
                }
            }
}

// ---------------- K5: fused attn, quarter-channel, scalar-fp32 PV ----------------
__global__ __launch_bounds__(256, 8) void attn_fused(const unsigned short* __restrict__ projh,
                                                     const unsigned short* __restrict__ projl,
                                                     const float* __restrict__ aarr,
                                                     const float* __restrict__ marr,
                                                     const float* __restrict__ csum,
                                                     unsigned short* __restrict__ ho_hi,
                                                     unsigned short* __restrict__ ho_lo,
                                                     float* __restrict__ psum) {
    __shared__ __attribute__((aligned(16))) float Vf[32 * 36];
    __shared__ __attribute__((aligned(16))) float Pf[4][16 * 36];
    __shared__ float al[32];

    // 2048 blocks = (bh, qt, ch-quarter); qtr-flip balances per-CU load (264 tiles/CU)
    const int idx = blockIdx.x;
    const int bh = idx & 15;
    const int qtr = idx >> 9;              // channel quarter 0..3
    int qt = (idx >> 4) & 31;
    if (qtr & 1) qt = 31 - qt;
    const int b = bh >> 3, h = bh & 7;
    const int tid = threadIdx.x, lane = tid & 63, w = tid >> 6;
    const int fr = lane & 15, fg = lane >> 4;
    const int q0 = qt * 64;

    // ---- QK-phase per-lane state ----
    bf16x8 qfh[4], qfl[4];
    {
        const size_t qoff = (size_t)(b * 2048 + q0 + 16 * w + fr) * 2304 + h * 128;
#pragma unroll
        for (int ks = 0; ks < 4; ks++) {
            qfh[ks] = __builtin_bit_cast(bf16x8, *(const us8*)(projh + qoff + ks * 32 + fg * 8));
            qfl[ks] = __builtin_bit_cast(bf16x8, *(const us8*)(projl + qoff + ks * 32 + fg * 8));
        }
    }
    float maqk[4];
#pragma unroll
    for (int r = 0; r < 4; r++)
        maqk[r] = marr[(size_t)bh * 2048 + q0 + 16 * w + fg * 4 + r];

    // ---- PV-phase per-lane state: 8 channels = qtr*32 + j4 + m*16 + e ----
    const int rpv = lane >> 2;
    const int j4 = (lane & 3) * 4;
    const int sgpv = q0 + 16 * w + rpv;
    f32x4 accs[2] = {};
    float b_run = 0.f;

    // staging ids (V quarter: 32 keys x 32 ch, 4 ch per thread)
    const int vrow = tid >> 3, vch = (tid & 7) * 4;
    const size_t kbase = (size_t)(b * 2048) * 2304 + 1024;
    const size_t vgbase = (size_t)(b * 2048) * 2304 + 1152 + qtr * 32;

    const int nt = 2 * qt + 2;
    us4 vh0, vl0;
    float a_st;
#define LOADT(T0)                                                              \
    {                                                                          \
        const size_t vo = vgbase + (size_t)((T0) + vrow) * 2304 + vch;         \
        vh0 = *(const us4*)(projh + vo);                                       \
        vl0 = *(const us4*)(projl + vo);                                       \
        a_st = (tid < 32) ? aarr[(size_t)bh * 2048 + (T0) + tid] : 0.f;        \
    }

    LOADT(0);
    for (int kt = 0; kt < nt; kt++) {
        const int t0 = kt * 32;
        __syncthreads();
        {
            f32x4 vv;
#pragma unroll
            for (int e = 0; e < 4; e++) vv[e] = bf2f(vh0[e]) + bf2f(vl0[e]);
            *(f32x4*)&Vf[vrow * 36 + vch] = vv;
        }
        if (tid < 32) al[tid] = a_st;
        __syncthreads();
        if (kt + 1 < nt) LOADT(t0 + 32);

        // QK^T 3-product MFMA, K fragments straight from global (L2-resident)
#pragma unroll
        for (int j = 0; j < 2; j++) {
            f32x4 sf = {};
            const size_t krow = kbase + (size_t)(t0 + j * 16 + fr) * 2304 + fg * 8;
            __builtin_amdgcn_s_setprio(1);
#pragma unroll
            for (int ks = 0; ks < 4; ks++) {
                bf16x8 kfh = __builtin_bit_cast(bf16x8, *(const us8*)(projh + krow + ks * 32));
                bf16x8 kfl = __builtin_bit_cast(bf16x8, *(const us8*)(projl + krow + ks * 32));
                sf = mfma16(qfh[ks], kfh, sf);
                sf = mfma16(qfh[ks], kfl, sf);
                sf = mfma16(qfl[ks], kfh, sf);
            }
            __builtin_amdgcn_s_setprio(0);
            const float atj = al[j * 16 + fr];
            const int key = t0 + j * 16 + fr;
#pragma unroll
            for (int r = 0; r < 4; r++) {
                const int sg = q0 + 16 * w + fg * 4 + r;
                float p = (key <= sg) ? sf[r] * __expf(atj - maqk[r]) : 0.f;
                Pf[w][(fg * 4 + r) * 36 + j * 16 + fr] = p;
            }
        }
        __asm__ volatile("s_waitcnt lgkmcnt(0)" ::: "memory");
        __builtin_amdgcn_sched_barrier(0);

        // scalar-fp32 PV: row rpv, 8 channels (2 chunks of 4)
        {
            const float* pr = &Pf[w][rpv * 36];
#pragma unroll
            for (int t4 = 0; t4 < 8; t4++) {
                f32x4 p4 = *(const f32x4*)&pr[t4 * 4];
#pragma unroll
                for (int e = 0; e < 4; e++) {
                    const float p = p4[e];
                    b_run += p;
                    const int t = t4 * 4 + e;
                    accs[0] += p * *(const f32x4*)&Vf[t * 36 + j4];
                    accs[1] += p * *(const f32x4*)&Vf[t * 36 + j4 + 16];
                }
            }
        }
    }
#undef LOADT

    // finalize: n-divide, write h (hi/lo) + partial LN sums
    const float cs_pv = csum[(size_t)bh * 2048 + sgpv];
    const float ma_pv = marr[(size_t)bh * 2048 + sgpv];
    const float nf = __expf(-(cs_pv + ma_pv));
    const float n = fmaxf(fabsf(b_run), nf);
    const float inv = 1.f / (n + 1e-6f);
    accs[0] *= inv;
    accs[1] *= inv;

    float s1 = 0.f, s2 = 0.f;
#pragma unroll
    for (int m = 0; m < 2; m++)
#pragma unroll
        for (int e = 0; e < 4; e++) {
            float v = accs[m][e];
            s1 += v;
            s2 += v * v;
        }
    s1 += __shfl_xor(s1, 1);
    s1 += __shfl_xor(s1, 2);
    s2 += __shfl_xor(s2, 1);
    s2 += __shfl_xor(s2, 2);

    const size_t hbase = (size_t)(b * 2048 + sgpv) * 1024 + h * 128 + qtr * 32 + j4;
#pragma unroll
    for (int m = 0; m < 2; m++) {
        us4 hi4, lo4;
#pragma unroll
        for (int e = 0; e < 4; e++) {
            float v = accs[m][e];
            unsigned short h1 = f2bf(v);
            hi4[e] = h1;
            lo4[e] = f2bf(v - bf2f(h1));
        }
        *(us4*)&ho_hi[hbase + m * 16] = hi4;
        *(us4*)&ho_lo[hbase + m * 16] = lo4;
    }
    if ((lane & 3) == 0) {
        const int rowid = bh * 2048 + sgpv;
        psum[(size_t)(qtr * 2 + 0) * 32768 + rowid] = s1;
        psum[(size_t)(qtr * 2 + 1) * 32768 + rowid] = s2;
    }
}

// ---------------- K5b: LayerNorm + og gate + re-split (in place) ----------------
__global__ __launch_bounds__(256) void ln_gate(unsigned short* __restrict__ ho_hi,
                                               unsigned short* __restrict__ ho_lo,
                                               const float* __restrict__ psum,
                                               const unsigned short* __restrict__ projh,
                                               const unsigned short* __restrict__ projl,
                                               const float* __restrict__ lnw) {
    const int row = blockIdx.x * 4 + (threadIdx.x >> 6);  // 0..32767 = (b,s,h)
    const int lane = threadIdx.x & 63;
    const int b = row >> 14;
    const int s = (row >> 3) & 2047;
    const int h = row & 7;
    const int rowid = (b * 8 + h) * 2048 + s;

    float s1 = 0.f, s2 = 0.f;
#pragma unroll
    for (int q = 0; q < 4; q++) {
        s1 += psum[(size_t)(2 * q + 0) * 32768 + rowid];
        s2 += psum[(size_t)(2 * q + 1) * 32768 + rowid];
    }
    const float mu = s1 * (1.f / 128.f);
    const float var = fmaxf(s2 * (1.f / 128.f) - mu * mu, 0.f);
    const float rstd = rsqrtf(var + 1e-6f);

    const int ch = lane * 2;
    const size_t hoff = (size_t)(row >> 3) * 1024 + h * 128 + ch;
    us2 hh = *(const us2*)&ho_hi[hoff];
    us2 hl = *(const us2*)&ho_lo[hoff];
    const float v0 = bf2f(hh[0]) + bf2f(hl[0]);
    const float v1 = bf2f(hh[1]) + bf2f(hl[1]);

    const size_t ogo = (size_t)(b * 2048 + s) * 2304 + 1280 + h * 128 + ch;
    us2 ogh = *(const us2*)&projh[ogo];
    us2 ogl = *(const us2*)&projl[ogo];
    const float og0 = bf2f(ogh[0]) + bf2f(ogl[0]);
    const float og1 = bf2f(ogh[1]) + bf2f(ogl[1]);
    const float sig0 = 1.f / (1.f + __expf(-og0));
    const float sig1 = 1.f / (1.f + __expf(-og1));

    f32x2 lw = *(const f32x2*)&lnw[h * 128 + ch];
    const float ho0 = (v0 - mu) * rstd * lw[0] * sig0;
    const float ho1 = (v1 - mu) * rstd * lw[1] * sig1;

    us2 oh, ol;
    unsigned short h0b = f2bf(ho0);
    unsigned short h1b = f2bf(ho1);
    oh[0] = h0b; oh[1] = h1b;
    ol[0] = f2bf(ho0 - bf2f(h0b));
    ol[1] = f2bf(ho1 - bf2f(h1b));
    *(us2*)&ho_hi[hoff] = oh;
    *(us2*)&ho_lo[hoff] = ol;
}

// ---------------------------------------------------------------------------
extern "C" void kernel_launch(void* const* d_in, const int* in_sizes, int n_in,
                              void* d_out, int out_size, void* d_ws, size_t ws_size,
                              hipStream_t stream) {
    (void)in_sizes; (void)n_in; (void)out_size; (void)ws_size;
    const float* x    = (const float*)d_in[0];
    const float* Wq   = (const float*)d_in[1];
    const float* Wk   = (const float*)d_in[2];
    const float* Wv   = (const float*)d_in[3];
    const float* Wog  = (const float*)d_in[4];
    const float* Wi   = (const float*)d_in[5];
    const float* bi   = (const float*)d_in[6];
    const float* Wf   = (const float*)d_in[7];
    const float* bfb  = (const float*)d_in[8];
    const float* lnw  = (const float*)d_in[9];
    const float* Wout = (const float*)d_in[10];

    char* p = (char*)d_ws;
    auto carve = [&](size_t bytes) -> char* {
        char* r = p;
        p += (bytes + 255) & ~(size_t)255;
        return r;
    };
    unsigned short* x_hi   = (unsigned short*)carve(4194304ull * 2);
    unsigned short* x_lo   = (unsigned short*)carve(4194304ull * 2);
    unsigned short* wc_hi  = (unsigned short*)carve(2359296ull * 2);
    unsigned short* wc_lo  = (unsigned short*)carve(2359296ull * 2);
    unsigned short* wo_hi  = (unsigned short*)carve(1048576ull * 2);
    unsigned short* wo_lo  = (unsigned short*)carve(1048576ull * 2);
    unsigned short* pr_hi  = (unsigned short*)carve(4096ull * 2304 * 2);
    unsigned short* pr_lo  = (unsigned short*)carve(4096ull * 2304 * 2);
    float* ipre    = (float*)carve(32768ull * 4);
    float* lgf_buf = (float*)carve(32768ull * 4);
    float* csum    = (float*)carve(32768ull * 4);
    float* aarr    = (float*)carve(32768ull * 4);
    float* marr    = (float*)carve(32768ull * 4);
    float* psum    = (float*)carve(8ull * 32768 * 4);
    unsigned short* ho_hi = x_hi;   // x dead after proj GEMM
    unsigned short* ho_lo = x_lo;

    k_split_bf16<<<16384, 256, 0, stream>>>(x, x_hi, x_lo, 4194304);
    build_wcat<<<(2359296 + 255) / 256, 256, 0, stream>>>(Wq, Wk, Wv, Wog, wc_hi, wc_lo);
    k_split_bf16<<<4096, 256, 0, stream>>>(Wout, wo_hi, wo_lo, 1048576);
    gates_kernel<<<4096, 256, 0, stream>>>(x, Wi, bi, Wf, bfb, ipre, lgf_buf);
    scan_kernel<<<16, 64, 0, stream>>>(ipre, lgf_buf, csum, aarr, marr);
    gemm_bt3<<<dim3(32, 18), 256, 0, stream>>>(x_hi, x_lo, wc_hi, wc_lo, pr_hi, pr_lo, 1024, 2304, 1);
    attn_fused<<<2048, 256, 0, stream>>>(pr_hi, pr_lo, aarr, marr, csum, ho_hi, ho_lo, psum);
    ln_gate<<<8192, 256, 0, stream>>>(ho_hi, ho_lo, psum, pr_hi, pr_lo, lnw);
    gemm_bt3<<<dim3(32, 8), 256, 0, stream>>>(ho_hi, ho_lo, wo_hi, wo_lo, d_out, nullptr, 1024, 1024, 0);
}

// Round 10
// 1053.924 us; speedup vs baseline: 1.2258x; 1.2258x over previous
//
#include <hip/hip_runtime.h>

// ---------------------------------------------------------------------------
// mLSTM block, MI355X. B=2,S=2048,D=1024,NH=8,DH=128.
// v9: quarter-channel attn (2048 blocks), K restored to LDS, 32.3KB LDS ->
//     5 blocks/CU, XCD b-locality swizzle + balanced rounds. v8 numerics.
// ---------------------------------------------------------------------------

typedef __bf16 bf16x8 __attribute__((ext_vector_type(8)));
typedef float f32x4 __attribute__((ext_vector_type(4)));
typedef float f32x2 __attribute__((ext_vector_type(2)));
typedef unsigned short us8 __attribute__((ext_vector_type(8)));
typedef unsigned short us4 __attribute__((ext_vector_type(4)));
typedef unsigned short us2 __attribute__((ext_vector_type(2)));

__device__ __forceinline__ unsigned short f2bf(float f) {
    unsigned int u = __builtin_bit_cast(unsigned int, f);
    unsigned int r = u + 0x7fffu + ((u >> 16) & 1u);
    return (unsigned short)(r >> 16);
}
__device__ __forceinline__ float bf2f(unsigned short h) {
    unsigned int u = ((unsigned int)h) << 16;
    return __builtin_bit_cast(float, u);
}
__device__ __forceinline__ f32x4 mfma16(bf16x8 a, bf16x8 b, f32x4 c) {
    return __builtin_amdgcn_mfma_f32_16x16x32_bf16(a, b, c, 0, 0, 0);
}

// ---------------- K0 ----------------
__global__ __launch_bounds__(256) void k_split_bf16(const float* __restrict__ in,
                                                    unsigned short* __restrict__ hi,
                                                    unsigned short* __restrict__ lo, int n) {
    int i = blockIdx.x * 256 + threadIdx.x;
    if (i < n) {
        float f = in[i];
        unsigned short h = f2bf(f);
        hi[i] = h;
        lo[i] = f2bf(f - bf2f(h));
    }
}

__global__ __launch_bounds__(256) void build_wcat(const float* __restrict__ Wq,
                                                  const float* __restrict__ Wk,
                                                  const float* __restrict__ Wv,
                                                  const float* __restrict__ Wog,
                                                  unsigned short* __restrict__ wh,
                                                  unsigned short* __restrict__ wl) {
    int idx = blockIdx.x * 256 + threadIdx.x;
    if (idx >= 2304 * 1024) return;
    int row = idx >> 10, col = idx & 1023;
    float v;
    if (row < 1024)      v = Wq[(size_t)row * 1024 + col] * 0.08838834764831845f;
    else if (row < 1152) v = Wk[(size_t)(row - 1024) * 1024 + col];
    else if (row < 1280) v = Wv[(size_t)(row - 1152) * 1024 + col];
    else                 v = Wog[(size_t)(row - 1280) * 1024 + col];
    unsigned short h = f2bf(v);
    wh[idx] = h;
    wl[idx] = f2bf(v - bf2f(h));
}

// ---------------- K1: gates ----------------
__global__ __launch_bounds__(256) void gates_kernel(const float* __restrict__ x,
                                                    const float* __restrict__ Wi,
                                                    const float* __restrict__ bi,
                                                    const float* __restrict__ Wf,
                                                    const float* __restrict__ bfb,
                                                    float* __restrict__ ipre,
                                                    float* __restrict__ lgf) {
    int bs = blockIdx.x;
    int b = bs >> 11, s = bs & 2047;
    const float* xr = x + (size_t)bs * 1024;
    int lane = threadIdx.x & 63, w = threadIdx.x >> 6;
    const float* W = (w < 2) ? Wi : Wf;
    int h0 = (w & 1) * 4;
    float dot0 = 0.f, dot1 = 0.f, dot2 = 0.f, dot3 = 0.f;
    for (int i = lane; i < 1024; i += 64) {
        float xv = xr[i];
        dot0 += xv * W[(size_t)(h0 + 0) * 1024 + i];
        dot1 += xv * W[(size_t)(h0 + 1) * 1024 + i];
        dot2 += xv * W[(size_t)(h0 + 2) * 1024 + i];
        dot3 += xv * W[(size_t)(h0 + 3) * 1024 + i];
    }
#pragma unroll
    for (int o = 32; o; o >>= 1) {
        dot0 += __shfl_xor(dot0, o);
        dot1 += __shfl_xor(dot1, o);
        dot2 += __shfl_xor(dot2, o);
        dot3 += __shfl_xor(dot3, o);
    }
    if (lane == 0) {
        float d[4] = {dot0, dot1, dot2, dot3};
#pragma unroll
        for (int j = 0; j < 4; j++) {
            int hh = h0 + j;
            if (w < 2) {
                float z = d[j] + bi[hh];
                z = 15.f * tanhf(z * (1.f / 15.f));
                ipre[((size_t)b * 8 + hh) * 2048 + s] = z;
            } else {
                float z = d[j] + bfb[hh];
                z = 15.f * tanhf(z * (1.f / 15.f));
                lgf[((size_t)b * 8 + hh) * 2048 + s] = fminf(z, 0.f) - log1pf(expf(-fabsf(z)));
            }
        }
    }
}

// ---------------- K2: scan ----------------
__global__ void scan_kernel(const float* __restrict__ ipre, const float* __restrict__ lgf,
                            float* __restrict__ csum, float* __restrict__ aarr,
                            float* __restrict__ marr) {
    int bh = blockIdx.x;
    int lane = threadIdx.x;
    const float* lf = lgf + (size_t)bh * 2048;
    const float* ip = ipre + (size_t)bh * 2048;
    float* cs = csum + (size_t)bh * 2048;
    float* aa = aarr + (size_t)bh * 2048;
    float* mm = marr + (size_t)bh * 2048;
    float carry = 0.f;
    float carrym = -1e30f;
    for (int c = 0; c < 32; c++) {
        float v = lf[c * 64 + lane];
#pragma unroll
        for (int o = 1; o < 64; o <<= 1) {
            float t = __shfl_up(v, o);
            if (lane >= o) v += t;
        }
        float cval = carry + v;
        cs[c * 64 + lane] = cval;
        float a = ip[c * 64 + lane] - cval;
        aa[c * 64 + lane] = a;
        float mv = a;
#pragma unroll
        for (int o = 1; o < 64; o <<= 1) {
            float t = __shfl_up(mv, o);
            if (lane >= o) mv = fmaxf(mv, t);
        }
        float mval = fmaxf(carrym, mv);
        mm[c * 64 + lane] = mval;
        carry = __shfl(cval, 63);
        carrym = __shfl(mval, 63);
    }
}

// ---- K3/K6: 3-product GEMM, 128x128 tile ----
__global__ __launch_bounds__(256) void gemm_bt3(const unsigned short* __restrict__ Ah,
                                                const unsigned short* __restrict__ Al,
                                                const unsigned short* __restrict__ Bh,
                                                const unsigned short* __restrict__ Bl,
                                                void* __restrict__ Cp,
                                                unsigned short* __restrict__ Clo,
                                                int K, int ldc, int c_bf16) {
    __shared__ __attribute__((aligned(16))) unsigned short Ash[128 * 40];
    __shared__ __attribute__((aligned(16))) unsigned short Asl[128 * 40];
    __shared__ __attribute__((aligned(16))) unsigned short Bsh[128 * 40];
    __shared__ __attribute__((aligned(16))) unsigned short Bsl[128 * 40];
    const int tid = threadIdx.x;
    const int lane = tid & 63, wv = tid >> 6;
    const int wr = wv >> 1, wc = wv & 1;
    const int fr = lane & 15, fg = lane >> 4;
    const int srow = tid >> 1, scol = (tid & 1) * 16;
    const size_t aoff = (size_t)(blockIdx.x * 128 + srow) * K + scol;
    const size_t boff = (size_t)(blockIdx.y * 128 + srow) * K + scol;
    f32x4 acc[4][4] = {};
    for (int kt = 0; kt < K; kt += 32) {
        us8 avh0 = *(const us8*)(Ah + aoff + kt);
        us8 avh1 = *(const us8*)(Ah + aoff + kt + 8);
        us8 avl0 = *(const us8*)(Al + aoff + kt);
        us8 avl1 = *(const us8*)(Al + aoff + kt + 8);
        us8 bvh0 = *(const us8*)(Bh + boff + kt);
        us8 bvh1 = *(const us8*)(Bh + boff + kt + 8);
        us8 bvl0 = *(const us8*)(Bl + boff + kt);
        us8 bvl1 = *(const us8*)(Bl + boff + kt + 8);
        __syncthreads();
        *(us8*)&Ash[srow * 40 + scol] = avh0;
        *(us8*)&Ash[srow * 40 + scol + 8] = avh1;
        *(us8*)&Asl[srow * 40 + scol] = avl0;
        *(us8*)&Asl[srow * 40 + scol + 8] = avl1;
        *(us8*)&Bsh[srow * 40 + scol] = bvh0;
        *(us8*)&Bsh[srow * 40 + scol + 8] = bvh1;
        *(us8*)&Bsl[srow * 40 + scol] = bvl0;
        *(us8*)&Bsl[srow * 40 + scol + 8] = bvl1;
        __syncthreads();
        bf16x8 bfh[4], bfl[4];
#pragma unroll
        for (int j = 0; j < 4; j++) {
            bfh[j] = __builtin_bit_cast(bf16x8, *(const us8*)&Bsh[(64 * wc + 16 * j + fr) * 40 + fg * 8]);
            bfl[j] = __builtin_bit_cast(bf16x8, *(const us8*)&Bsl[(64 * wc + 16 * j + fr) * 40 + fg * 8]);
        }
        __builtin_amdgcn_s_setprio(1);
#pragma unroll
        for (int i = 0; i < 4; i++) {
            bf16x8 afh = __builtin_bit_cast(bf16x8, *(const us8*)&Ash[(64 * wr + 16 * i + fr) * 40 + fg * 8]);
            bf16x8 afl = __builtin_bit_cast(bf16x8, *(const us8*)&Asl[(64 * wr + 16 * i + fr) * 40 + fg * 8]);
#pragma unroll
            for (int j = 0; j < 4; j++) {
                acc[i][j] = mfma16(afh, bfh[j], acc[i][j]);
                acc[i][j] = mfma16(afh, bfl[j], acc[i][j]);
                acc[i][j] = mfma16(afl, bfh[j], acc[i][j]);
            }
        }
        __builtin_amdgcn_s_setprio(0);
    }
#pragma unroll
    for (int i = 0; i < 4; i++)
#pragma unroll
        for (int j = 0; j < 4; j++)
#pragma unroll
            for (int e = 0; e < 4; e++) {
                int r = blockIdx.x * 128 + 64 * wr + 16 * i + fg * 4 + e;
                int c = blockIdx.y * 128 + 64 * wc + 16 * j + fr;
                float v = acc[i][j][e];
                if (c_bf16) {
                    unsigned short h = f2bf(v);
                    ((unsigned short*)Cp)[(size_t)r * ldc + c] = h;
                    Clo[(size_t)r * ldc + c] = f2bf(v - bf2f(h));
                } else {
                    ((float*)Cp)[(size_t)r * ldc + c] = v;
                }
            }
}

// ---------------- K5: fused attn, quarter-channel, K in LDS, XCD swizzle ----
__global__ __launch_bounds__(256, 5) void attn_fused(const unsigned short* __restrict__ projh,
                                                     const unsigned short* __restrict__ projl,
                                                     const float* __restrict__ aarr,
                                                     const float* __restrict__ marr,
                                                     const float* __restrict__ csum,
                                                     unsigned short* __restrict__ ho_hi,
                                                     unsigned short* __restrict__ ho_lo,
                                                     float* __restrict__ psum) {
    __shared__ __attribute__((aligned(16))) unsigned short Klh[32 * 148];
    __shared__ __attribute__((aligned(16))) unsigned short Kll[32 * 148];
    __shared__ __attribute__((aligned(16))) float Vf[32 * 36];   // col 32: a[]
    __shared__ __attribute__((aligned(16))) float Pf[4][16 * 34];

    // 2048 blocks. XCD = bid%8 heuristic: XCDs 0-3 own b=0, 4-7 own b=1.
    // Per XCD: 256 slots = 8 rounds x 32 CUs; rounds alternate qt=c / 31-c
    // so every CU's 8 blocks total 264 tiles (constant).
    const int bid = blockIdx.x;
    const int xcd = bid & 7, slot = bid >> 3;
    const int b = (xcd >> 2) & 1;
    const int l = xcd & 3;
    const int r = slot >> 5, c = slot & 31;
    const int qt = (r & 1) ? (31 - c) : c;
    const int idx16 = l * 8 + r;              // 0..31
    const int h = idx16 >> 2, chq = idx16 & 3;
    const int bh = b * 8 + h;
    const int tid = threadIdx.x, lane = tid & 63, w = tid >> 6;
    const int fr = lane & 15, fg = lane >> 4;
    const int q0 = qt * 64;

    // ---- QK-phase per-lane state ----
    bf16x8 qfh[4], qfl[4];
    {
        const size_t qoff = (size_t)(b * 2048 + q0 + 16 * w + fr) * 2304 + h * 128;
#pragma unroll
        for (int ks = 0; ks < 4; ks++) {
            qfh[ks] = __builtin_bit_cast(bf16x8, *(const us8*)(projh + qoff + ks * 32 + fg * 8));
            qfl[ks] = __builtin_bit_cast(bf16x8, *(const us8*)(projl + qoff + ks * 32 + fg * 8));
        }
    }
    float maqk[4];
#pragma unroll
    for (int rr = 0; rr < 4; rr++)
        maqk[rr] = marr[(size_t)bh * 2048 + q0 + 16 * w + fg * 4 + rr];

    // ---- PV-phase per-lane state: 8 channels = chq*32 + j4 + m*16 + e ----
    const int rpv = lane >> 2;
    const int j4 = (lane & 3) * 4;
    const int sgpv = q0 + 16 * w + rpv;
    f32x4 accs[2] = {};
    float b_run = 0.f;

    // staging ids
    const int kr = tid >> 3, kc = (tid & 7) * 16;
    const int vrow = tid >> 3, vch = (tid & 7) * 4;
    const size_t kbase = (size_t)(b * 2048) * 2304 + 1024;
    const size_t vgbase = (size_t)(b * 2048) * 2304 + 1152 + chq * 32;

    const int nt = 2 * qt + 2;
    us8 kh0, kh1, kl0, kl1;
    us4 vh0, vl0;
    float a_st;
#define LOADT(T0)                                                              \
    {                                                                          \
        const size_t ko = kbase + (size_t)((T0) + kr) * 2304 + kc;             \
        const size_t vo = vgbase + (size_t)((T0) + vrow) * 2304 + vch;         \
        kh0 = *(const us8*)(projh + ko);                                       \
        kh1 = *(const us8*)(projh + ko + 8);                                   \
        kl0 = *(const us8*)(projl + ko);                                       \
        kl1 = *(const us8*)(projl + ko + 8);                                   \
        vh0 = *(const us4*)(projh + vo);                                       \
        vl0 = *(const us4*)(projl + vo);                                       \
        a_st = (tid < 32) ? aarr[(size_t)bh * 2048 + (T0) + tid] : 0.f;        \
    }

    LOADT(0);
    for (int kt = 0; kt < nt; kt++) {
        const int t0 = kt * 32;
        __syncthreads();
        *(us8*)&Klh[kr * 148 + kc] = kh0;
        *(us8*)&Klh[kr * 148 + kc + 8] = kh1;
        *(us8*)&Kll[kr * 148 + kc] = kl0;
        *(us8*)&Kll[kr * 148 + kc + 8] = kl1;
        {
            f32x4 vv;
#pragma unroll
            for (int e = 0; e < 4; e++) vv[e] = bf2f(vh0[e]) + bf2f(vl0[e]);
            *(f32x4*)&Vf[vrow * 36 + vch] = vv;
        }
        if (tid < 32) Vf[tid * 36 + 32] = a_st;
        __syncthreads();
        if (kt + 1 < nt) LOADT(t0 + 32);

        // QK^T 3-product MFMA from LDS; P final-valued via exact prefix-max
#pragma unroll
        for (int j = 0; j < 2; j++) {
            f32x4 sf = {};
            __builtin_amdgcn_s_setprio(1);
#pragma unroll
            for (int ks = 0; ks < 4; ks++) {
                bf16x8 kfh = __builtin_bit_cast(bf16x8, *(const us8*)&Klh[(j * 16 + fr) * 148 + ks * 32 + fg * 8]);
                bf16x8 kfl = __builtin_bit_cast(bf16x8, *(const us8*)&Kll[(j * 16 + fr) * 148 + ks * 32 + fg * 8]);
                sf = mfma16(qfh[ks], kfh, sf);
                sf = mfma16(qfh[ks], kfl, sf);
                sf = mfma16(qfl[ks], kfh, sf);
            }
            __builtin_amdgcn_s_setprio(0);
            const float atj = Vf[(j * 16 + fr) * 36 + 32];
            const int key = t0 + j * 16 + fr;
#pragma unroll
            for (int rr = 0; rr < 4; rr++) {
                const int sg = q0 + 16 * w + fg * 4 + rr;
                float p = (key <= sg) ? sf[rr] * __expf(atj - maqk[rr]) : 0.f;
                Pf[w][(fg * 4 + rr) * 34 + j * 16 + fr] = p;
            }
        }
        __asm__ volatile("s_waitcnt lgkmcnt(0)" ::: "memory");
        __builtin_amdgcn_sched_barrier(0);

        // scalar-fp32 PV: row rpv, 8 channels (2 chunks of 4)
        {
            const float* pr = &Pf[w][rpv * 34];
#pragma unroll
            for (int t4 = 0; t4 < 8; t4++) {
                f32x4 p4 = *(const f32x4*)&pr[t4 * 4];
#pragma unroll
                for (int e = 0; e < 4; e++) {
                    const float p = p4[e];
                    b_run += p;
                    const int t = t4 * 4 + e;
                    accs[0] += p * *(const f32x4*)&Vf[t * 36 + j4];
                    accs[1] += p * *(const f32x4*)&Vf[t * 36 + j4 + 16];
                }
            }
        }
    }
#undef LOADT

    // finalize: n-divide, write h (hi/lo) + partial LN sums
    const float cs_pv = csum[(size_t)bh * 2048 + sgpv];
    const float ma_pv = marr[(size_t)bh * 2048 + sgpv];
    const float nf = __expf(-(cs_pv + ma_pv));
    const float n = fmaxf(fabsf(b_run), nf);
    const float inv = 1.f / (n + 1e-6f);
    accs[0] *= inv;
    accs[1] *= inv;

    float s1 = 0.f, s2 = 0.f;
#pragma unroll
    for (int m = 0; m < 2; m++)
#pragma unroll
        for (int e = 0; e < 4; e++) {
            float v = accs[m][e];
            s1 += v;
            s2 += v * v;
        }
    s1 += __shfl_xor(s1, 1);
    s1 += __shfl_xor(s1, 2);
    s2 += __shfl_xor(s2, 1);
    s2 += __shfl_xor(s2, 2);

    const size_t hbase = (size_t)(b * 2048 + sgpv) * 1024 + h * 128 + chq * 32 + j4;
#pragma unroll
    for (int m = 0; m < 2; m++) {
        us4 hi4, lo4;
#pragma unroll
        for (int e = 0; e < 4; e++) {
            float v = accs[m][e];
            unsigned short h1 = f2bf(v);
            hi4[e] = h1;
            lo4[e] = f2bf(v - bf2f(h1));
        }
        *(us4*)&ho_hi[hbase + m * 16] = hi4;
        *(us4*)&ho_lo[hbase + m * 16] = lo4;
    }
    if ((lane & 3) == 0) {
        const int rowid = bh * 2048 + sgpv;
        psum[(size_t)(chq * 2 + 0) * 32768 + rowid] = s1;
        psum[(size_t)(chq * 2 + 1) * 32768 + rowid] = s2;
    }
}

// ---------------- K5b: LayerNorm + og gate + re-split (in place) ----------------
__global__ __launch_bounds__(256) void ln_gate(unsigned short* __restrict__ ho_hi,
                                               unsigned short* __restrict__ ho_lo,
                                               const float* __restrict__ psum,
                                               const unsigned short* __restrict__ projh,
                                               const unsigned short* __restrict__ projl,
                                               const float* __restrict__ lnw) {
    const int row = blockIdx.x * 4 + (threadIdx.x >> 6);  // 0..32767 = (b,s,h)
    const int lane = threadIdx.x & 63;
    const int b = row >> 14;
    const int s = (row >> 3) & 2047;
    const int h = row & 7;
    const int rowid = (b * 8 + h) * 2048 + s;

    float s1 = 0.f, s2 = 0.f;
#pragma unroll
    for (int q = 0; q < 4; q++) {
        s1 += psum[(size_t)(2 * q + 0) * 32768 + rowid];
        s2 += psum[(size_t)(2 * q + 1) * 32768 + rowid];
    }
    const float mu = s1 * (1.f / 128.f);
    const float var = fmaxf(s2 * (1.f / 128.f) - mu * mu, 0.f);
    const float rstd = rsqrtf(var + 1e-6f);

    const int ch = lane * 2;
    const size_t hoff = (size_t)(row >> 3) * 1024 + h * 128 + ch;
    us2 hh = *(const us2*)&ho_hi[hoff];
    us2 hl = *(const us2*)&ho_lo[hoff];
    const float v0 = bf2f(hh[0]) + bf2f(hl[0]);
    const float v1 = bf2f(hh[1]) + bf2f(hl[1]);

    const size_t ogo = (size_t)(b * 2048 + s) * 2304 + 1280 + h * 128 + ch;
    us2 ogh = *(const us2*)&projh[ogo];
    us2 ogl = *(const us2*)&projl[ogo];
    const float og0 = bf2f(ogh[0]) + bf2f(ogl[0]);
    const float og1 = bf2f(ogh[1]) + bf2f(ogl[1]);
    const float sig0 = 1.f / (1.f + __expf(-og0));
    const float sig1 = 1.f / (1.f + __expf(-og1));

    f32x2 lw = *(const f32x2*)&lnw[h * 128 + ch];
    const float ho0 = (v0 - mu) * rstd * lw[0] * sig0;
    const float ho1 = (v1 - mu) * rstd * lw[1] * sig1;

    us2 oh, ol;
    unsigned short h0b = f2bf(ho0);
    unsigned short h1b = f2bf(ho1);
    oh[0] = h0b; oh[1] = h1b;
    ol[0] = f2bf(ho0 - bf2f(h0b));
    ol[1] = f2bf(ho1 - bf2f(h1b));
    *(us2*)&ho_hi[hoff] = oh;
    *(us2*)&ho_lo[hoff] = ol;
}

// ---------------------------------------------------------------------------
extern "C" void kernel_launch(void* const* d_in, const int* in_sizes, int n_in,
                              void* d_out, int out_size, void* d_ws, size_t ws_size,
                              hipStream_t stream) {
    (void)in_sizes; (void)n_in; (void)out_size; (void)ws_size;
    const float* x    = (const float*)d_in[0];
    const float* Wq   = (const float*)d_in[1];
    const float* Wk   = (const float*)d_in[2];
    const float* Wv   = (const float*)d_in[3];
    const float* Wog  = (const float*)d_in[4];
    const float* Wi   = (const float*)d_in[5];
    const float* bi   = (const float*)d_in[6];
    const float* Wf   = (const float*)d_in[7];
    const float* bfb  = (const float*)d_in[8];
    const float* lnw  = (const float*)d_in[9];
    const float* Wout = (const float*)d_in[10];

    char* p = (char*)d_ws;
    auto carve = [&](size_t bytes) -> char* {
        char* r = p;
        p += (bytes + 255) & ~(size_t)255;
        return r;
    };
    unsigned short* x_hi   = (unsigned short*)carve(4194304ull * 2);
    unsigned short* x_lo   = (unsigned short*)carve(4194304ull * 2);
    unsigned short* wc_hi  = (unsigned short*)carve(2359296ull * 2);
    unsigned short* wc_lo  = (unsigned short*)carve(2359296ull * 2);
    unsigned short* wo_hi  = (unsigned short*)carve(1048576ull * 2);
    unsigned short* wo_lo  = (unsigned short*)carve(1048576ull * 2);
    unsigned short* pr_hi  = (unsigned short*)carve(4096ull * 2304 * 2);
    unsigned short* pr_lo  = (unsigned short*)carve(4096ull * 2304 * 2);
    float* ipre    = (float*)carve(32768ull * 4);
    float* lgf_buf = (float*)carve(32768ull * 4);
    float* csum    = (float*)carve(32768ull * 4);
    float* aarr    = (float*)carve(32768ull * 4);
    float* marr    = (float*)carve(32768ull * 4);
    float* psum    = (float*)carve(8ull * 32768 * 4);
    unsigned short* ho_hi = x_hi;   // x dead after proj GEMM
    unsigned short* ho_lo = x_lo;

    k_split_bf16<<<16384, 256, 0, stream>>>(x, x_hi, x_lo, 4194304);
    build_wcat<<<(2359296 + 255) / 256, 256, 0, stream>>>(Wq, Wk, Wv, Wog, wc_hi, wc_lo);
    k_split_bf16<<<4096, 256, 0, stream>>>(Wout, wo_hi, wo_lo, 1048576);
    gates_kernel<<<4096, 256, 0, stream>>>(x, Wi, bi, Wf, bfb, ipre, lgf_buf);
    scan_kernel<<<16, 64, 0, stream>>>(ipre, lgf_buf, csum, aarr, marr);
    gemm_bt3<<<dim3(32, 18), 256, 0, stream>>>(x_hi, x_lo, wc_hi, wc_lo, pr_hi, pr_lo, 1024, 2304, 1);
    attn_fused<<<2048, 256, 0, stream>>>(pr_hi, pr_lo, aarr, marr, csum, ho_hi, ho_lo, psum);
    ln_gate<<<8192, 256, 0, stream>>>(ho_hi, ho_lo, psum, pr_hi, pr_lo, lnw);
    gemm_bt3<<<dim3(32, 8), 256, 0, stream>>>(ho_hi, ho_lo, wo_hi, wo_lo, d_out, nullptr, 1024, 1024, 0);
}

// Round 11
// 468.200 us; speedup vs baseline: 2.7594x; 2.2510x over previous
//
#include <hip/hip_runtime.h>

// ---------------------------------------------------------------------------
// mLSTM block, MI355X. B=2,S=2048,D=1024,NH=8,DH=128.
// v10: swapped-operand QK (S^T) + in-register P relayout (shfl) + MFMA PV.
//      No P LDS (race surface deleted). LN fused back in-block.
// ---------------------------------------------------------------------------

typedef __bf16 bf16x8 __attribute__((ext_vector_type(8)));
typedef float f32x4 __attribute__((ext_vector_type(4)));
typedef unsigned short us8 __attribute__((ext_vector_type(8)));
typedef unsigned short us4 __attribute__((ext_vector_type(4)));

__device__ __forceinline__ unsigned short f2bf(float f) {
    unsigned int u = __builtin_bit_cast(unsigned int, f);
    unsigned int r = u + 0x7fffu + ((u >> 16) & 1u);
    return (unsigned short)(r >> 16);
}
__device__ __forceinline__ float bf2f(unsigned short h) {
    unsigned int u = ((unsigned int)h) << 16;
    return __builtin_bit_cast(float, u);
}
__device__ __forceinline__ f32x4 mfma16(bf16x8 a, bf16x8 b, f32x4 c) {
    return __builtin_amdgcn_mfma_f32_16x16x32_bf16(a, b, c, 0, 0, 0);
}

// ---------------- K0 ----------------
__global__ __launch_bounds__(256) void k_split_bf16(const float* __restrict__ in,
                                                    unsigned short* __restrict__ hi,
                                                    unsigned short* __restrict__ lo, int n) {
    int i = blockIdx.x * 256 + threadIdx.x;
    if (i < n) {
        float f = in[i];
        unsigned short h = f2bf(f);
        hi[i] = h;
        lo[i] = f2bf(f - bf2f(h));
    }
}

__global__ __launch_bounds__(256) void build_wcat(const float* __restrict__ Wq,
                                                  const float* __restrict__ Wk,
                                                  const float* __restrict__ Wv,
                                                  const float* __restrict__ Wog,
                                                  unsigned short* __restrict__ wh,
                                                  unsigned short* __restrict__ wl) {
    int idx = blockIdx.x * 256 + threadIdx.x;
    if (idx >= 2304 * 1024) return;
    int row = idx >> 10, col = idx & 1023;
    float v;
    if (row < 1024)      v = Wq[(size_t)row * 1024 + col] * 0.08838834764831845f;
    else if (row < 1152) v = Wk[(size_t)(row - 1024) * 1024 + col];
    else if (row < 1280) v = Wv[(size_t)(row - 1152) * 1024 + col];
    else                 v = Wog[(size_t)(row - 1280) * 1024 + col];
    unsigned short h = f2bf(v);
    wh[idx] = h;
    wl[idx] = f2bf(v - bf2f(h));
}

// ---------------- K1: gates ----------------
__global__ __launch_bounds__(256) void gates_kernel(const float* __restrict__ x,
                                                    const float* __restrict__ Wi,
                                                    const float* __restrict__ bi,
                                                    const float* __restrict__ Wf,
                                                    const float* __restrict__ bfb,
                                                    float* __restrict__ ipre,
                                                    float* __restrict__ lgf) {
    int bs = blockIdx.x;
    int b = bs >> 11, s = bs & 2047;
    const float* xr = x + (size_t)bs * 1024;
    int lane = threadIdx.x & 63, w = threadIdx.x >> 6;
    const float* W = (w < 2) ? Wi : Wf;
    int h0 = (w & 1) * 4;
    float dot0 = 0.f, dot1 = 0.f, dot2 = 0.f, dot3 = 0.f;
    for (int i = lane; i < 1024; i += 64) {
        float xv = xr[i];
        dot0 += xv * W[(size_t)(h0 + 0) * 1024 + i];
        dot1 += xv * W[(size_t)(h0 + 1) * 1024 + i];
        dot2 += xv * W[(size_t)(h0 + 2) * 1024 + i];
        dot3 += xv * W[(size_t)(h0 + 3) * 1024 + i];
    }
#pragma unroll
    for (int o = 32; o; o >>= 1) {
        dot0 += __shfl_xor(dot0, o);
        dot1 += __shfl_xor(dot1, o);
        dot2 += __shfl_xor(dot2, o);
        dot3 += __shfl_xor(dot3, o);
    }
    if (lane == 0) {
        float d[4] = {dot0, dot1, dot2, dot3};
#pragma unroll
        for (int j = 0; j < 4; j++) {
            int hh = h0 + j;
            if (w < 2) {
                float z = d[j] + bi[hh];
                z = 15.f * tanhf(z * (1.f / 15.f));
                ipre[((size_t)b * 8 + hh) * 2048 + s] = z;
            } else {
                float z = d[j] + bfb[hh];
                z = 15.f * tanhf(z * (1.f / 15.f));
                lgf[((size_t)b * 8 + hh) * 2048 + s] = fminf(z, 0.f) - log1pf(expf(-fabsf(z)));
            }
        }
    }
}

// ---------------- K2: scan ----------------
__global__ void scan_kernel(const float* __restrict__ ipre, const float* __restrict__ lgf,
                            float* __restrict__ csum, float* __restrict__ aarr,
                            float* __restrict__ marr) {
    int bh = blockIdx.x;
    int lane = threadIdx.x;
    const float* lf = lgf + (size_t)bh * 2048;
    const float* ip = ipre + (size_t)bh * 2048;
    float* cs = csum + (size_t)bh * 2048;
    float* aa = aarr + (size_t)bh * 2048;
    float* mm = marr + (size_t)bh * 2048;
    float carry = 0.f;
    float carrym = -1e30f;
    for (int c = 0; c < 32; c++) {
        float v = lf[c * 64 + lane];
#pragma unroll
        for (int o = 1; o < 64; o <<= 1) {
            float t = __shfl_up(v, o);
            if (lane >= o) v += t;
        }
        float cval = carry + v;
        cs[c * 64 + lane] = cval;
        float a = ip[c * 64 + lane] - cval;
        aa[c * 64 + lane] = a;
        float mv = a;
#pragma unroll
        for (int o = 1; o < 64; o <<= 1) {
            float t = __shfl_up(mv, o);
            if (lane >= o) mv = fmaxf(mv, t);
        }
        float mval = fmaxf(carrym, mv);
        mm[c * 64 + lane] = mval;
        carry = __shfl(cval, 63);
        carrym = __shfl(mval, 63);
    }
}

// ---- K3/K6: 3-product GEMM, 128x128 tile ----
__global__ __launch_bounds__(256) void gemm_bt3(const unsigned short* __restrict__ Ah,
                                                const unsigned short* __restrict__ Al,
                                                const unsigned short* __restrict__ Bh,
                                                const unsigned short* __restrict__ Bl,
                                                void* __restrict__ Cp,
                                                unsigned short* __restrict__ Clo,
                                                int K, int ldc, int c_bf16) {
    __shared__ __attribute__((aligned(16))) unsigned short Ash[128 * 40];
    __shared__ __attribute__((aligned(16))) unsigned short Asl[128 * 40];
    __shared__ __attribute__((aligned(16))) unsigned short Bsh[128 * 40];
    __shared__ __attribute__((aligned(16))) unsigned short Bsl[128 * 40];
    const int tid = threadIdx.x;
    const int lane = tid & 63, wv = tid >> 6;
    const int wr = wv >> 1, wc = wv & 1;
    const int fr = lane & 15, fg = lane >> 4;
    const int srow = tid >> 1, scol = (tid & 1) * 16;
    const size_t aoff = (size_t)(blockIdx.x * 128 + srow) * K + scol;
    const size_t boff = (size_t)(blockIdx.y * 128 + srow) * K + scol;
    f32x4 acc[4][4] = {};
    for (int kt = 0; kt < K; kt += 32) {
        us8 avh0 = *(const us8*)(Ah + aoff + kt);
        us8 avh1 = *(const us8*)(Ah + aoff + kt + 8);
        us8 avl0 = *(const us8*)(Al + aoff + kt);
        us8 avl1 = *(const us8*)(Al + aoff + kt + 8);
        us8 bvh0 = *(const us8*)(Bh + boff + kt);
        us8 bvh1 = *(const us8*)(Bh + boff + kt + 8);
        us8 bvl0 = *(const us8*)(Bl + boff + kt);
        us8 bvl1 = *(const us8*)(Bl + boff + kt + 8);
        __syncthreads();
        *(us8*)&Ash[srow * 40 + scol] = avh0;
        *(us8*)&Ash[srow * 40 + scol + 8] = avh1;
        *(us8*)&Asl[srow * 40 + scol] = avl0;
        *(us8*)&Asl[srow * 40 + scol + 8] = avl1;
        *(us8*)&Bsh[srow * 40 + scol] = bvh0;
        *(us8*)&Bsh[srow * 40 + scol + 8] = bvh1;
        *(us8*)&Bsl[srow * 40 + scol] = bvl0;
        *(us8*)&Bsl[srow * 40 + scol + 8] = bvl1;
        __syncthreads();
        bf16x8 bfh[4], bfl[4];
#pragma unroll
        for (int j = 0; j < 4; j++) {
            bfh[j] = __builtin_bit_cast(bf16x8, *(const us8*)&Bsh[(64 * wc + 16 * j + fr) * 40 + fg * 8]);
            bfl[j] = __builtin_bit_cast(bf16x8, *(const us8*)&Bsl[(64 * wc + 16 * j + fr) * 40 + fg * 8]);
        }
        __builtin_amdgcn_s_setprio(1);
#pragma unroll
        for (int i = 0; i < 4; i++) {
            bf16x8 afh = __builtin_bit_cast(bf16x8, *(const us8*)&Ash[(64 * wr + 16 * i + fr) * 40 + fg * 8]);
            bf16x8 afl = __builtin_bit_cast(bf16x8, *(const us8*)&Asl[(64 * wr + 16 * i + fr) * 40 + fg * 8]);
#pragma unroll
            for (int j = 0; j < 4; j++) {
                acc[i][j] = mfma16(afh, bfh[j], acc[i][j]);
                acc[i][j] = mfma16(afh, bfl[j], acc[i][j]);
                acc[i][j] = mfma16(afl, bfh[j], acc[i][j]);
            }
        }
        __builtin_amdgcn_s_setprio(0);
    }
#pragma unroll
    for (int i = 0; i < 4; i++)
#pragma unroll
        for (int j = 0; j < 4; j++)
#pragma unroll
            for (int e = 0; e < 4; e++) {
                int r = blockIdx.x * 128 + 64 * wr + 16 * i + fg * 4 + e;
                int c = blockIdx.y * 128 + 64 * wc + 16 * j + fr;
                float v = acc[i][j][e];
                if (c_bf16) {
                    unsigned short h = f2bf(v);
                    ((unsigned short*)Cp)[(size_t)r * ldc + c] = h;
                    Clo[(size_t)r * ldc + c] = f2bf(v - bf2f(h));
                } else {
                    ((float*)Cp)[(size_t)r * ldc + c] = v;
                }
            }
}

// ---------------- K4: vT[b][c][s] (hi/lo) ----------------
__global__ __launch_bounds__(256) void make_vt(const unsigned short* __restrict__ ph,
                                               const unsigned short* __restrict__ pl,
                                               unsigned short* __restrict__ vTh,
                                               unsigned short* __restrict__ vTl) {
    int i = blockIdx.x * 256 + threadIdx.x;
    if (i >= 524288) return;
    int s = i & 2047, c = (i >> 11) & 127, b = i >> 18;
    size_t src = ((size_t)(b * 2048 + s)) * 2304 + 1152 + c;
    vTh[i] = ph[src];
    vTl[i] = pl[src];
}

// ---------------- K5: fused attn — S^T QK + in-register P + MFMA PV + LN ----
__global__ __launch_bounds__(256, 4) void attn_fused(const unsigned short* __restrict__ projh,
                                                     const unsigned short* __restrict__ projl,
                                                     const unsigned short* __restrict__ vTh,
                                                     const unsigned short* __restrict__ vTl,
                                                     const float* __restrict__ aarr,
                                                     const float* __restrict__ marr,
                                                     const float* __restrict__ csum,
                                                     const float* __restrict__ lnw,
                                                     unsigned short* __restrict__ ho_hi,
                                                     unsigned short* __restrict__ ho_lo) {
    __shared__ __attribute__((aligned(16))) unsigned short Klh[32 * 148];
    __shared__ __attribute__((aligned(16))) unsigned short Kll[32 * 148];
    __shared__ float al[32];

    // 512 blocks; (i, i+256) -> (bh,qt),(bh,31-qt) complementary pairing
    const int idx = blockIdx.x;
    const int half = idx >> 8;
    const int pid = idx & 255;
    const int bh = pid & 15;
    const int qt0 = pid >> 4;
    const int qt = half ? (31 - qt0) : qt0;
    const int b = bh >> 3, h = bh & 7;
    const int tid = threadIdx.x, lane = tid & 63, w = tid >> 6;
    const int fr = lane & 15, fg = lane >> 4;
    const int q0 = qt * 64;
    const int qg = q0 + 16 * w + fr;          // this lane's q row

    // Q fragments hi/lo (B-operand layout, col=fr)
    bf16x8 qfh[4], qfl[4];
    {
        const size_t qoff = (size_t)(b * 2048 + qg) * 2304 + h * 128;
#pragma unroll
        for (int ks = 0; ks < 4; ks++) {
            qfh[ks] = __builtin_bit_cast(bf16x8, *(const us8*)(projh + qoff + ks * 32 + fg * 8));
            qfl[ks] = __builtin_bit_cast(bf16x8, *(const us8*)(projl + qoff + ks * 32 + fg * 8));
        }
    }
    const float ma_q = marr[(size_t)bh * 2048 + qg];

    f32x4 acc[8] = {};
    float b_run = 0.f;

    const int kr = tid >> 3, kc = (tid & 7) * 16;
    const size_t kbase = (size_t)(b * 2048) * 2304 + 1024;
    const size_t vtbase = (size_t)b * 128 * 2048;

    const int nt = 2 * qt + 2;
    us8 kh0, kh1, kl0, kl1;
    float a_st;
#define LOADT(T0)                                                              \
    {                                                                          \
        const size_t ko = kbase + (size_t)((T0) + kr) * 2304 + kc;             \
        kh0 = *(const us8*)(projh + ko);                                       \
        kh1 = *(const us8*)(projh + ko + 8);                                   \
        kl0 = *(const us8*)(projl + ko);                                       \
        kl1 = *(const us8*)(projl + ko + 8);                                   \
        a_st = (tid < 32) ? aarr[(size_t)bh * 2048 + (T0) + tid] : 0.f;        \
    }

    LOADT(0);
    for (int kt = 0; kt < nt; kt++) {
        const int t0 = kt * 32;
        __syncthreads();
        *(us8*)&Klh[kr * 148 + kc] = kh0;
        *(us8*)&Klh[kr * 148 + kc + 8] = kh1;
        *(us8*)&Kll[kr * 148 + kc] = kl0;
        *(us8*)&Kll[kr * 148 + kc + 8] = kl1;
        if (tid < 32) al[tid] = a_st;
        __syncthreads();
        if (kt + 1 < nt) LOADT(t0 + 32);

        // S^T = mfma(K, Q): D[key(row), q(col)]; exp/mask in D-domain
        float dj[2][4];
#pragma unroll
        for (int j = 0; j < 2; j++) {
            f32x4 sf = {};
            __builtin_amdgcn_s_setprio(1);
#pragma unroll
            for (int ks = 0; ks < 4; ks++) {
                bf16x8 kfh = __builtin_bit_cast(bf16x8, *(const us8*)&Klh[(j * 16 + fr) * 148 + ks * 32 + fg * 8]);
                bf16x8 kfl = __builtin_bit_cast(bf16x8, *(const us8*)&Kll[(j * 16 + fr) * 148 + ks * 32 + fg * 8]);
                sf = mfma16(kfh, qfh[ks], sf);
                sf = mfma16(kfh, qfl[ks], sf);
                sf = mfma16(kfl, qfh[ks], sf);
            }
            __builtin_amdgcn_s_setprio(0);
#pragma unroll
            for (int r = 0; r < 4; r++) {
                const int kloc = j * 16 + fg * 4 + r;
                const int key = t0 + kloc;
                const float atv = al[kloc];
                dj[j][r] = (key <= qg) ? sf[r] * __expf(atv - ma_q) : 0.f;
            }
        }

        // b_run: sum over the 32 keys for q=fr (replicated over fg)
        {
            float ts = dj[0][0] + dj[0][1] + dj[0][2] + dj[0][3]
                     + dj[1][0] + dj[1][1] + dj[1][2] + dj[1][3];
            ts += __shfl_xor(ts, 16);
            ts += __shfl_xor(ts, 32);
            b_run += ts;
        }

        // D-frag -> B-frag relayout (in-register): p8[e] = P[q=fr][k=8g+e]
        float p8[8];
        const int srlo = 32 * ((lane >> 4) & 1) + fr;
#pragma unroll
        for (int e = 0; e < 8; e++) {
            const int sl = srlo + ((e >= 4) ? 16 : 0);
            const float v0 = __shfl(dj[0][e & 3], sl);
            const float v1 = __shfl(dj[1][e & 3], sl);
            p8[e] = (lane & 32) ? v1 : v0;
        }
        us8 phu, plu;
#pragma unroll
        for (int e = 0; e < 8; e++) {
            unsigned short hh = f2bf(p8[e]);
            phu[e] = hh;
            plu[e] = f2bf(p8[e] - bf2f(hh));
        }
        const bf16x8 pfh = __builtin_bit_cast(bf16x8, phu);
        const bf16x8 pfl = __builtin_bit_cast(bf16x8, plu);

        // PV: O^T[ch, q] += mfma(V^T, P)
        __builtin_amdgcn_s_setprio(1);
#pragma unroll
        for (int jb = 0; jb < 8; jb++) {
            const size_t vo = vtbase + (size_t)(jb * 16 + fr) * 2048 + t0 + fg * 8;
            bf16x8 vfh = __builtin_bit_cast(bf16x8, *(const us8*)(vTh + vo));
            bf16x8 vfl = __builtin_bit_cast(bf16x8, *(const us8*)(vTl + vo));
            acc[jb] = mfma16(vfh, pfh, acc[jb]);
            acc[jb] = mfma16(vfh, pfl, acc[jb]);
            acc[jb] = mfma16(vfl, pfh, acc[jb]);
        }
        __builtin_amdgcn_s_setprio(0);
    }
#undef LOADT

    // finalize: per-lane q=fr, 32 channels ch = jb*16 + fg*4 + r
    const float cs_q = csum[(size_t)bh * 2048 + qg];
    const float nf = __expf(-(cs_q + ma_q));
    const float n = fmaxf(fabsf(b_run), nf);
    const float inv = 1.f / (n + 1e-6f);
#pragma unroll
    for (int jb = 0; jb < 8; jb++) acc[jb] *= inv;

    float s1 = 0.f;
#pragma unroll
    for (int jb = 0; jb < 8; jb++) s1 += acc[jb][0] + acc[jb][1] + acc[jb][2] + acc[jb][3];
    s1 += __shfl_xor(s1, 16);
    s1 += __shfl_xor(s1, 32);
    const float mu = s1 * (1.f / 128.f);
    float vv = 0.f;
#pragma unroll
    for (int jb = 0; jb < 8; jb++)
#pragma unroll
        for (int e = 0; e < 4; e++) {
            float d = acc[jb][e] - mu;
            vv += d * d;
        }
    vv += __shfl_xor(vv, 16);
    vv += __shfl_xor(vv, 32);
    const float rstd = rsqrtf(vv * (1.f / 128.f) + 1e-6f);

    const size_t obase = (size_t)(b * 2048 + qg) * 2304 + 1280 + h * 128 + fg * 4;
    const size_t hbase = (size_t)(b * 2048 + qg) * 1024 + h * 128 + fg * 4;
#pragma unroll
    for (int jb = 0; jb < 8; jb++) {
        us4 ogh = *(const us4*)(projh + obase + jb * 16);
        us4 ogl = *(const us4*)(projl + obase + jb * 16);
        f32x4 lw = *(const f32x4*)&lnw[h * 128 + jb * 16 + fg * 4];
        us4 hi4, lo4;
#pragma unroll
        for (int e = 0; e < 4; e++) {
            const float og = bf2f(ogh[e]) + bf2f(ogl[e]);
            const float sig = 1.f / (1.f + __expf(-og));
            const float ho = (acc[jb][e] - mu) * rstd * lw[e] * sig;
            unsigned short h1 = f2bf(ho);
            hi4[e] = h1;
            lo4[e] = f2bf(ho - bf2f(h1));
        }
        *(us4*)&ho_hi[hbase + jb * 16] = hi4;
        *(us4*)&ho_lo[hbase + jb * 16] = lo4;
    }
}

// ---------------------------------------------------------------------------
extern "C" void kernel_launch(void* const* d_in, const int* in_sizes, int n_in,
                              void* d_out, int out_size, void* d_ws, size_t ws_size,
                              hipStream_t stream) {
    (void)in_sizes; (void)n_in; (void)out_size; (void)ws_size;
    const float* x    = (const float*)d_in[0];
    const float* Wq   = (const float*)d_in[1];
    const float* Wk   = (const float*)d_in[2];
    const float* Wv   = (const float*)d_in[3];
    const float* Wog  = (const float*)d_in[4];
    const float* Wi   = (const float*)d_in[5];
    const float* bi   = (const float*)d_in[6];
    const float* Wf   = (const float*)d_in[7];
    const float* bfb  = (const float*)d_in[8];
    const float* lnw  = (const float*)d_in[9];
    const float* Wout = (const float*)d_in[10];

    char* p = (char*)d_ws;
    auto carve = [&](size_t bytes) -> char* {
        char* r = p;
        p += (bytes + 255) & ~(size_t)255;
        return r;
    };
    unsigned short* x_hi   = (unsigned short*)carve(4194304ull * 2);
    unsigned short* x_lo   = (unsigned short*)carve(4194304ull * 2);
    unsigned short* wc_hi  = (unsigned short*)carve(2359296ull * 2);
    unsigned short* wc_lo  = (unsigned short*)carve(2359296ull * 2);
    unsigned short* wo_hi  = (unsigned short*)carve(1048576ull * 2);
    unsigned short* wo_lo  = (unsigned short*)carve(1048576ull * 2);
    unsigned short* pr_hi  = (unsigned short*)carve(4096ull * 2304 * 2);
    unsigned short* pr_lo  = (unsigned short*)carve(4096ull * 2304 * 2);
    unsigned short* vT_hi  = (unsigned short*)carve(524288ull * 2);
    unsigned short* vT_lo  = (unsigned short*)carve(524288ull * 2);
    float* ipre    = (float*)carve(32768ull * 4);
    float* lgf_buf = (float*)carve(32768ull * 4);
    float* csum    = (float*)carve(32768ull * 4);
    float* aarr    = (float*)carve(32768ull * 4);
    float* marr    = (float*)carve(32768ull * 4);
    unsigned short* ho_hi = x_hi;   // x dead after proj GEMM
    unsigned short* ho_lo = x_lo;

    k_split_bf16<<<16384, 256, 0, stream>>>(x, x_hi, x_lo, 4194304);
    build_wcat<<<(2359296 + 255) / 256, 256, 0, stream>>>(Wq, Wk, Wv, Wog, wc_hi, wc_lo);
    k_split_bf16<<<4096, 256, 0, stream>>>(Wout, wo_hi, wo_lo, 1048576);
    gates_kernel<<<4096, 256, 0, stream>>>(x, Wi, bi, Wf, bfb, ipre, lgf_buf);
    scan_kernel<<<16, 64, 0, stream>>>(ipre, lgf_buf, csum, aarr, marr);
    gemm_bt3<<<dim3(32, 18), 256, 0, stream>>>(x_hi, x_lo, wc_hi, wc_lo, pr_hi, pr_lo, 1024, 2304, 1);
    make_vt<<<2048, 256, 0, stream>>>(pr_hi, pr_lo, vT_hi, vT_lo);
    attn_fused<<<512, 256, 0, stream>>>(pr_hi, pr_lo, vT_hi, vT_lo, aarr, marr, csum, lnw, ho_hi, ho_lo);
    gemm_bt3<<<dim3(32, 8), 256, 0, stream>>>(ho_hi, ho_lo, wo_hi, wo_lo, d_out, nullptr, 1024, 1024, 0);
}

// Round 12
// 326.896 us; speedup vs baseline: 3.9522x; 1.4323x over previous
//
#include <hip/hip_runtime.h>

// ---------------------------------------------------------------------------
// mLSTM block, MI355X. B=2,S=2048,D=1024,NH=8,DH=128.
// v11: v10 + V^T staged in LDS (prefetched). Bitwise-identical numerics to v10.
//      S^T QK (swapped operands) + in-register P relayout + MFMA PV + fused LN.
// ---------------------------------------------------------------------------

typedef __bf16 bf16x8 __attribute__((ext_vector_type(8)));
typedef float f32x4 __attribute__((ext_vector_type(4)));
typedef unsigned short us8 __attribute__((ext_vector_type(8)));
typedef unsigned short us4 __attribute__((ext_vector_type(4)));

__device__ __forceinline__ unsigned short f2bf(float f) {
    unsigned int u = __builtin_bit_cast(unsigned int, f);
    unsigned int r = u + 0x7fffu + ((u >> 16) & 1u);
    return (unsigned short)(r >> 16);
}
__device__ __forceinline__ float bf2f(unsigned short h) {
    unsigned int u = ((unsigned int)h) << 16;
    return __builtin_bit_cast(float, u);
}
__device__ __forceinline__ f32x4 mfma16(bf16x8 a, bf16x8 b, f32x4 c) {
    return __builtin_amdgcn_mfma_f32_16x16x32_bf16(a, b, c, 0, 0, 0);
}

// ---------------- K0 ----------------
__global__ __launch_bounds__(256) void k_split_bf16(const float* __restrict__ in,
                                                    unsigned short* __restrict__ hi,
                                                    unsigned short* __restrict__ lo, int n) {
    int i = blockIdx.x * 256 + threadIdx.x;
    if (i < n) {
        float f = in[i];
        unsigned short h = f2bf(f);
        hi[i] = h;
        lo[i] = f2bf(f - bf2f(h));
    }
}

__global__ __launch_bounds__(256) void build_wcat(const float* __restrict__ Wq,
                                                  const float* __restrict__ Wk,
                                                  const float* __restrict__ Wv,
                                                  const float* __restrict__ Wog,
                                                  unsigned short* __restrict__ wh,
                                                  unsigned short* __restrict__ wl) {
    int idx = blockIdx.x * 256 + threadIdx.x;
    if (idx >= 2304 * 1024) return;
    int row = idx >> 10, col = idx & 1023;
    float v;
    if (row < 1024)      v = Wq[(size_t)row * 1024 + col] * 0.08838834764831845f;
    else if (row < 1152) v = Wk[(size_t)(row - 1024) * 1024 + col];
    else if (row < 1280) v = Wv[(size_t)(row - 1152) * 1024 + col];
    else                 v = Wog[(size_t)(row - 1280) * 1024 + col];
    unsigned short h = f2bf(v);
    wh[idx] = h;
    wl[idx] = f2bf(v - bf2f(h));
}

// ---------------- K1: gates ----------------
__global__ __launch_bounds__(256) void gates_kernel(const float* __restrict__ x,
                                                    const float* __restrict__ Wi,
                                                    const float* __restrict__ bi,
                                                    const float* __restrict__ Wf,
                                                    const float* __restrict__ bfb,
                                                    float* __restrict__ ipre,
                                                    float* __restrict__ lgf) {
    int bs = blockIdx.x;
    int b = bs >> 11, s = bs & 2047;
    const float* xr = x + (size_t)bs * 1024;
    int lane = threadIdx.x & 63, w = threadIdx.x >> 6;
    const float* W = (w < 2) ? Wi : Wf;
    int h0 = (w & 1) * 4;
    float dot0 = 0.f, dot1 = 0.f, dot2 = 0.f, dot3 = 0.f;
    for (int i = lane; i < 1024; i += 64) {
        float xv = xr[i];
        dot0 += xv * W[(size_t)(h0 + 0) * 1024 + i];
        dot1 += xv * W[(size_t)(h0 + 1) * 1024 + i];
        dot2 += xv * W[(size_t)(h0 + 2) * 1024 + i];
        dot3 += xv * W[(size_t)(h0 + 3) * 1024 + i];
    }
#pragma unroll
    for (int o = 32; o; o >>= 1) {
        dot0 += __shfl_xor(dot0, o);
        dot1 += __shfl_xor(dot1, o);
        dot2 += __shfl_xor(dot2, o);
        dot3 += __shfl_xor(dot3, o);
    }
    if (lane == 0) {
        float d[4] = {dot0, dot1, dot2, dot3};
#pragma unroll
        for (int j = 0; j < 4; j++) {
            int hh = h0 + j;
            if (w < 2) {
                float z = d[j] + bi[hh];
                z = 15.f * tanhf(z * (1.f / 15.f));
                ipre[((size_t)b * 8 + hh) * 2048 + s] = z;
            } else {
                float z = d[j] + bfb[hh];
                z = 15.f * tanhf(z * (1.f / 15.f));
                lgf[((size_t)b * 8 + hh) * 2048 + s] = fminf(z, 0.f) - log1pf(expf(-fabsf(z)));
            }
        }
    }
}

// ---------------- K2: scan ----------------
__global__ void scan_kernel(const float* __restrict__ ipre, const float* __restrict__ lgf,
                            float* __restrict__ csum, float* __restrict__ aarr,
                            float* __restrict__ marr) {
    int bh = blockIdx.x;
    int lane = threadIdx.x;
    const float* lf = lgf + (size_t)bh * 2048;
    const float* ip = ipre + (size_t)bh * 2048;
    float* cs = csum + (size_t)bh * 2048;
    float* aa = aarr + (size_t)bh * 2048;
    float* mm = marr + (size_t)bh * 2048;
    float carry = 0.f;
    float carrym = -1e30f;
    for (int c = 0; c < 32; c++) {
        float v = lf[c * 64 + lane];
#pragma unroll
        for (int o = 1; o < 64; o <<= 1) {
            float t = __shfl_up(v, o);
            if (lane >= o) v += t;
        }
        float cval = carry + v;
        cs[c * 64 + lane] = cval;
        float a = ip[c * 64 + lane] - cval;
        aa[c * 64 + lane] = a;
        float mv = a;
#pragma unroll
        for (int o = 1; o < 64; o <<= 1) {
            float t = __shfl_up(mv, o);
            if (lane >= o) mv = fmaxf(mv, t);
        }
        float mval = fmaxf(carrym, mv);
        mm[c * 64 + lane] = mval;
        carry = __shfl(cval, 63);
        carrym = __shfl(mval, 63);
    }
}

// ---- K3/K6: 3-product GEMM, 128x128 tile ----
__global__ __launch_bounds__(256) void gemm_bt3(const unsigned short* __restrict__ Ah,
                                                const unsigned short* __restrict__ Al,
                                                const unsigned short* __restrict__ Bh,
                                                const unsigned short* __restrict__ Bl,
                                                void* __restrict__ Cp,
                                                unsigned short* __restrict__ Clo,
                                                int K, int ldc, int c_bf16) {
    __shared__ __attribute__((aligned(16))) unsigned short Ash[128 * 40];
    __shared__ __attribute__((aligned(16))) unsigned short Asl[128 * 40];
    __shared__ __attribute__((aligned(16))) unsigned short Bsh[128 * 40];
    __shared__ __attribute__((aligned(16))) unsigned short Bsl[128 * 40];
    const int tid = threadIdx.x;
    const int lane = tid & 63, wv = tid >> 6;
    const int wr = wv >> 1, wc = wv & 1;
    const int fr = lane & 15, fg = lane >> 4;
    const int srow = tid >> 1, scol = (tid & 1) * 16;
    const size_t aoff = (size_t)(blockIdx.x * 128 + srow) * K + scol;
    const size_t boff = (size_t)(blockIdx.y * 128 + srow) * K + scol;
    f32x4 acc[4][4] = {};
    for (int kt = 0; kt < K; kt += 32) {
        us8 avh0 = *(const us8*)(Ah + aoff + kt);
        us8 avh1 = *(const us8*)(Ah + aoff + kt + 8);
        us8 avl0 = *(const us8*)(Al + aoff + kt);
        us8 avl1 = *(const us8*)(Al + aoff + kt + 8);
        us8 bvh0 = *(const us8*)(Bh + boff + kt);
        us8 bvh1 = *(const us8*)(Bh + boff + kt + 8);
        us8 bvl0 = *(const us8*)(Bl + boff + kt);
        us8 bvl1 = *(const us8*)(Bl + boff + kt + 8);
        __syncthreads();
        *(us8*)&Ash[srow * 40 + scol] = avh0;
        *(us8*)&Ash[srow * 40 + scol + 8] = avh1;
        *(us8*)&Asl[srow * 40 + scol] = avl0;
        *(us8*)&Asl[srow * 40 + scol + 8] = avl1;
        *(us8*)&Bsh[srow * 40 + scol] = bvh0;
        *(us8*)&Bsh[srow * 40 + scol + 8] = bvh1;
        *(us8*)&Bsl[srow * 40 + scol] = bvl0;
        *(us8*)&Bsl[srow * 40 + scol + 8] = bvl1;
        __syncthreads();
        bf16x8 bfh[4], bfl[4];
#pragma unroll
        for (int j = 0; j < 4; j++) {
            bfh[j] = __builtin_bit_cast(bf16x8, *(const us8*)&Bsh[(64 * wc + 16 * j + fr) * 40 + fg * 8]);
            bfl[j] = __builtin_bit_cast(bf16x8, *(const us8*)&Bsl[(64 * wc + 16 * j + fr) * 40 + fg * 8]);
        }
        __builtin_amdgcn_s_setprio(1);
#pragma unroll
        for (int i = 0; i < 4; i++) {
            bf16x8 afh = __builtin_bit_cast(bf16x8, *(const us8*)&Ash[(64 * wr + 16 * i + fr) * 40 + fg * 8]);
            bf16x8 afl = __builtin_bit_cast(bf16x8, *(const us8*)&Asl[(64 * wr + 16 * i + fr) * 40 + fg * 8]);
#pragma unroll
            for (int j = 0; j < 4; j++) {
                acc[i][j] = mfma16(afh, bfh[j], acc[i][j]);
                acc[i][j] = mfma16(afh, bfl[j], acc[i][j]);
                acc[i][j] = mfma16(afl, bfh[j], acc[i][j]);
            }
        }
        __builtin_amdgcn_s_setprio(0);
    }
#pragma unroll
    for (int i = 0; i < 4; i++)
#pragma unroll
        for (int j = 0; j < 4; j++)
#pragma unroll
            for (int e = 0; e < 4; e++) {
                int r = blockIdx.x * 128 + 64 * wr + 16 * i + fg * 4 + e;
                int c = blockIdx.y * 128 + 64 * wc + 16 * j + fr;
                float v = acc[i][j][e];
                if (c_bf16) {
                    unsigned short h = f2bf(v);
                    ((unsigned short*)Cp)[(size_t)r * ldc + c] = h;
                    Clo[(size_t)r * ldc + c] = f2bf(v - bf2f(h));
                } else {
                    ((float*)Cp)[(size_t)r * ldc + c] = v;
                }
            }
}

// ---------------- K4: vT[b][c][s] (hi/lo) ----------------
__global__ __launch_bounds__(256) void make_vt(const unsigned short* __restrict__ ph,
                                               const unsigned short* __restrict__ pl,
                                               unsigned short* __restrict__ vTh,
                                               unsigned short* __restrict__ vTl) {
    int i = blockIdx.x * 256 + threadIdx.x;
    if (i >= 524288) return;
    int s = i & 2047, c = (i >> 11) & 127, b = i >> 18;
    size_t src = ((size_t)(b * 2048 + s)) * 2304 + 1152 + c;
    vTh[i] = ph[src];
    vTl[i] = pl[src];
}

// ---------------- K5: fused attn — S^T QK + reg-P + MFMA PV (V in LDS) + LN --
__global__ __launch_bounds__(256, 2) void attn_fused(const unsigned short* __restrict__ projh,
                                                     const unsigned short* __restrict__ projl,
                                                     const unsigned short* __restrict__ vTh,
                                                     const unsigned short* __restrict__ vTl,
                                                     const float* __restrict__ aarr,
                                                     const float* __restrict__ marr,
                                                     const float* __restrict__ csum,
                                                     const float* __restrict__ lnw,
                                                     unsigned short* __restrict__ ho_hi,
                                                     unsigned short* __restrict__ ho_lo) {
    __shared__ __attribute__((aligned(16))) unsigned short Klh[32 * 148];
    __shared__ __attribute__((aligned(16))) unsigned short Kll[32 * 148];
    __shared__ __attribute__((aligned(16))) unsigned short Vlh[128 * 40];
    __shared__ __attribute__((aligned(16))) unsigned short Vll[128 * 40];
    __shared__ float al[32];

    // 512 blocks; (i, i+256) -> (bh,qt),(bh,31-qt) complementary pairing
    const int idx = blockIdx.x;
    const int half = idx >> 8;
    const int pid = idx & 255;
    const int bh = pid & 15;
    const int qt0 = pid >> 4;
    const int qt = half ? (31 - qt0) : qt0;
    const int b = bh >> 3, h = bh & 7;
    const int tid = threadIdx.x, lane = tid & 63, w = tid >> 6;
    const int fr = lane & 15, fg = lane >> 4;
    const int q0 = qt * 64;
    const int qg = q0 + 16 * w + fr;          // this lane's q row

    // Q fragments hi/lo (B-operand layout, col=fr)
    bf16x8 qfh[4], qfl[4];
    {
        const size_t qoff = (size_t)(b * 2048 + qg) * 2304 + h * 128;
#pragma unroll
        for (int ks = 0; ks < 4; ks++) {
            qfh[ks] = __builtin_bit_cast(bf16x8, *(const us8*)(projh + qoff + ks * 32 + fg * 8));
            qfl[ks] = __builtin_bit_cast(bf16x8, *(const us8*)(projl + qoff + ks * 32 + fg * 8));
        }
    }
    const float ma_q = marr[(size_t)bh * 2048 + qg];

    f32x4 acc[8] = {};
    float b_run = 0.f;

    const int kr = tid >> 3, kc = (tid & 7) * 16;   // K staging
    const int vr = tid >> 1, vc = (tid & 1) * 16;   // V^T staging: row=ch, col=key
    const size_t kbase = (size_t)(b * 2048) * 2304 + 1024;
    const size_t vtbase = (size_t)b * 128 * 2048;

    const int nt = 2 * qt + 2;
    us8 kh0, kh1, kl0, kl1, vh0, vh1, vl0, vl1;
    float a_st;
#define LOADT(T0)                                                              \
    {                                                                          \
        const size_t ko = kbase + (size_t)((T0) + kr) * 2304 + kc;             \
        const size_t vo = vtbase + (size_t)vr * 2048 + (T0) + vc;              \
        kh0 = *(const us8*)(projh + ko);                                       \
        kh1 = *(const us8*)(projh + ko + 8);                                   \
        kl0 = *(const us8*)(projl + ko);                                       \
        kl1 = *(const us8*)(projl + ko + 8);                                   \
        vh0 = *(const us8*)(vTh + vo);                                         \
        vh1 = *(const us8*)(vTh + vo + 8);                                     \
        vl0 = *(const us8*)(vTl + vo);                                         \
        vl1 = *(const us8*)(vTl + vo + 8);                                     \
        a_st = (tid < 32) ? aarr[(size_t)bh * 2048 + (T0) + tid] : 0.f;        \
    }

    LOADT(0);
    for (int kt = 0; kt < nt; kt++) {
        const int t0 = kt * 32;
        __syncthreads();
        *(us8*)&Klh[kr * 148 + kc] = kh0;
        *(us8*)&Klh[kr * 148 + kc + 8] = kh1;
        *(us8*)&Kll[kr * 148 + kc] = kl0;
        *(us8*)&Kll[kr * 148 + kc + 8] = kl1;
        *(us8*)&Vlh[vr * 40 + vc] = vh0;
        *(us8*)&Vlh[vr * 40 + vc + 8] = vh1;
        *(us8*)&Vll[vr * 40 + vc] = vl0;
        *(us8*)&Vll[vr * 40 + vc + 8] = vl1;
        if (tid < 32) al[tid] = a_st;
        __syncthreads();
        if (kt + 1 < nt) LOADT(t0 + 32);

        // S^T = mfma(K, Q): D[key(row), q(col)]; exp/mask in D-domain
        float dj[2][4];
#pragma unroll
        for (int j = 0; j < 2; j++) {
            f32x4 sf = {};
            __builtin_amdgcn_s_setprio(1);
#pragma unroll
            for (int ks = 0; ks < 4; ks++) {
                bf16x8 kfh = __builtin_bit_cast(bf16x8, *(const us8*)&Klh[(j * 16 + fr) * 148 + ks * 32 + fg * 8]);
                bf16x8 kfl = __builtin_bit_cast(bf16x8, *(const us8*)&Kll[(j * 16 + fr) * 148 + ks * 32 + fg * 8]);
                sf = mfma16(kfh, qfh[ks], sf);
                sf = mfma16(kfh, qfl[ks], sf);
                sf = mfma16(kfl, qfh[ks], sf);
            }
            __builtin_amdgcn_s_setprio(0);
#pragma unroll
            for (int r = 0; r < 4; r++) {
                const int kloc = j * 16 + fg * 4 + r;
                const int key = t0 + kloc;
                const float atv = al[kloc];
                dj[j][r] = (key <= qg) ? sf[r] * __expf(atv - ma_q) : 0.f;
            }
        }

        // b_run: sum over the 32 keys for q=fr (replicated over fg)
        {
            float ts = dj[0][0] + dj[0][1] + dj[0][2] + dj[0][3]
                     + dj[1][0] + dj[1][1] + dj[1][2] + dj[1][3];
            ts += __shfl_xor(ts, 16);
            ts += __shfl_xor(ts, 32);
            b_run += ts;
        }

        // D-frag -> B-frag relayout (in-register): p8[e] = P[q=fr][k=8g+e]
        float p8[8];
        const int srlo = 32 * ((lane >> 4) & 1) + fr;
#pragma unroll
        for (int e = 0; e < 8; e++) {
            const int sl = srlo + ((e >= 4) ? 16 : 0);
            const float v0 = __shfl(dj[0][e & 3], sl);
            const float v1 = __shfl(dj[1][e & 3], sl);
            p8[e] = (lane & 32) ? v1 : v0;
        }
        us8 phu, plu;
#pragma unroll
        for (int e = 0; e < 8; e++) {
            unsigned short hh = f2bf(p8[e]);
            phu[e] = hh;
            plu[e] = f2bf(p8[e] - bf2f(hh));
        }
        const bf16x8 pfh = __builtin_bit_cast(bf16x8, phu);
        const bf16x8 pfl = __builtin_bit_cast(bf16x8, plu);

        // PV: O^T[ch, q] += mfma(V^T, P), V^T from LDS
        __builtin_amdgcn_s_setprio(1);
#pragma unroll
        for (int jb = 0; jb < 8; jb++) {
            bf16x8 vfh = __builtin_bit_cast(bf16x8, *(const us8*)&Vlh[(jb * 16 + fr) * 40 + fg * 8]);
            bf16x8 vfl = __builtin_bit_cast(bf16x8, *(const us8*)&Vll[(jb * 16 + fr) * 40 + fg * 8]);
            acc[jb] = mfma16(vfh, pfh, acc[jb]);
            acc[jb] = mfma16(vfh, pfl, acc[jb]);
            acc[jb] = mfma16(vfl, pfh, acc[jb]);
        }
        __builtin_amdgcn_s_setprio(0);
    }
#undef LOADT

    // finalize: per-lane q=fr, 32 channels ch = jb*16 + fg*4 + r
    const float cs_q = csum[(size_t)bh * 2048 + qg];
    const float nf = __expf(-(cs_q + ma_q));
    const float n = fmaxf(fabsf(b_run), nf);
    const float inv = 1.f / (n + 1e-6f);
#pragma unroll
    for (int jb = 0; jb < 8; jb++) acc[jb] *= inv;

    float s1 = 0.f;
#pragma unroll
    for (int jb = 0; jb < 8; jb++) s1 += acc[jb][0] + acc[jb][1] + acc[jb][2] + acc[jb][3];
    s1 += __shfl_xor(s1, 16);
    s1 += __shfl_xor(s1, 32);
    const float mu = s1 * (1.f / 128.f);
    float vv = 0.f;
#pragma unroll
    for (int jb = 0; jb < 8; jb++)
#pragma unroll
        for (int e = 0; e < 4; e++) {
            float d = acc[jb][e] - mu;
            vv += d * d;
        }
    vv += __shfl_xor(vv, 16);
    vv += __shfl_xor(vv, 32);
    const float rstd = rsqrtf(vv * (1.f / 128.f) + 1e-6f);

    const size_t obase = (size_t)(b * 2048 + qg) * 2304 + 1280 + h * 128 + fg * 4;
    const size_t hbase = (size_t)(b * 2048 + qg) * 1024 + h * 128 + fg * 4;
#pragma unroll
    for (int jb = 0; jb < 8; jb++) {
        us4 ogh = *(const us4*)(projh + obase + jb * 16);
        us4 ogl = *(const us4*)(projl + obase + jb * 16);
        f32x4 lw = *(const f32x4*)&lnw[h * 128 + jb * 16 + fg * 4];
        us4 hi4, lo4;
#pragma unroll
        for (int e = 0; e < 4; e++) {
            const float og = bf2f(ogh[e]) + bf2f(ogl[e]);
            const float sig = 1.f / (1.f + __expf(-og));
            const float ho = (acc[jb][e] - mu) * rstd * lw[e] * sig;
            unsigned short h1 = f2bf(ho);
            hi4[e] = h1;
            lo4[e] = f2bf(ho - bf2f(h1));
        }
        *(us4*)&ho_hi[hbase + jb * 16] = hi4;
        *(us4*)&ho_lo[hbase + jb * 16] = lo4;
    }
}

// ---------------------------------------------------------------------------
extern "C" void kernel_launch(void* const* d_in, const int* in_sizes, int n_in,
                              void* d_out, int out_size, void* d_ws, size_t ws_size,
                              hipStream_t stream) {
    (void)in_sizes; (void)n_in; (void)out_size; (void)ws_size;
    const float* x    = (const float*)d_in[0];
    const float* Wq   = (const float*)d_in[1];
    const float* Wk   = (const float*)d_in[2];
    const float* Wv   = (const float*)d_in[3];
    const float* Wog  = (const float*)d_in[4];
    const float* Wi   = (const float*)d_in[5];
    const float* bi   = (const float*)d_in[6];
    const float* Wf   = (const float*)d_in[7];
    const float* bfb  = (const float*)d_in[8];
    const float* lnw  = (const float*)d_in[9];
    const float* Wout = (const float*)d_in[10];

    char* p = (char*)d_ws;
    auto carve = [&](size_t bytes) -> char* {
        char* r = p;
        p += (bytes + 255) & ~(size_t)255;
        return r;
    };
    unsigned short* x_hi   = (unsigned short*)carve(4194304ull * 2);
    unsigned short* x_lo   = (unsigned short*)carve(4194304ull * 2);
    unsigned short* wc_hi  = (unsigned short*)carve(2359296ull * 2);
    unsigned short* wc_lo  = (unsigned short*)carve(2359296ull * 2);
    unsigned short* wo_hi  = (unsigned short*)carve(1048576ull * 2);
    unsigned short* wo_lo  = (unsigned short*)carve(1048576ull * 2);
    unsigned short* pr_hi  = (unsigned short*)carve(4096ull * 2304 * 2);
    unsigned short* pr_lo  = (unsigned short*)carve(4096ull * 2304 * 2);
    unsigned short* vT_hi  = (unsigned short*)carve(524288ull * 2);
    unsigned short* vT_lo  = (unsigned short*)carve(524288ull * 2);
    float* ipre    = (float*)carve(32768ull * 4);
    float* lgf_buf = (float*)carve(32768ull * 4);
    float* csum    = (float*)carve(32768ull * 4);
    float* aarr    = (float*)carve(32768ull * 4);
    float* marr    = (float*)carve(32768ull * 4);
    unsigned short* ho_hi = x_hi;   // x dead after proj GEMM
    unsigned short* ho_lo = x_lo;

    k_split_bf16<<<16384, 256, 0, stream>>>(x, x_hi, x_lo, 4194304);
    build_wcat<<<(2359296 + 255) / 256, 256, 0, stream>>>(Wq, Wk, Wv, Wog, wc_hi, wc_lo);
    k_split_bf16<<<4096, 256, 0, stream>>>(Wout, wo_hi, wo_lo, 1048576);
    gates_kernel<<<4096, 256, 0, stream>>>(x, Wi, bi, Wf, bfb, ipre, lgf_buf);
    scan_kernel<<<16, 64, 0, stream>>>(ipre, lgf_buf, csum, aarr, marr);
    gemm_bt3<<<dim3(32, 18), 256, 0, stream>>>(x_hi, x_lo, wc_hi, wc_lo, pr_hi, pr_lo, 1024, 2304, 1);
    make_vt<<<2048, 256, 0, stream>>>(pr_hi, pr_lo, vT_hi, vT_lo);
    attn_fused<<<512, 256, 0, stream>>>(pr_hi, pr_lo, vT_hi, vT_lo, aarr, marr, csum, lnw, ho_hi, ho_lo);
    gemm_bt3<<<dim3(32, 8), 256, 0, stream>>>(ho_hi, ho_lo, wo_hi, wo_lo, d_out, nullptr, 1024, 1024, 0);
}

// Round 13
// 319.540 us; speedup vs baseline: 4.0431x; 1.0230x over previous
//
#include <hip/hip_runtime.h>

// ---------------------------------------------------------------------------
// mLSTM block, MI355X. B=2,S=2048,D=1024,NH=8,DH=128.
// v12: v11 + ping-pong LDS dbuf (1 barrier/tile), QK 3-acc split (ILP),
//      coalesced make_vt. Numerics = v11 modulo QK reassociation.
// ---------------------------------------------------------------------------

typedef __bf16 bf16x8 __attribute__((ext_vector_type(8)));
typedef float f32x4 __attribute__((ext_vector_type(4)));
typedef unsigned short us8 __attribute__((ext_vector_type(8)));
typedef unsigned short us4 __attribute__((ext_vector_type(4)));

__device__ __forceinline__ unsigned short f2bf(float f) {
    unsigned int u = __builtin_bit_cast(unsigned int, f);
    unsigned int r = u + 0x7fffu + ((u >> 16) & 1u);
    return (unsigned short)(r >> 16);
}
__device__ __forceinline__ float bf2f(unsigned short h) {
    unsigned int u = ((unsigned int)h) << 16;
    return __builtin_bit_cast(float, u);
}
__device__ __forceinline__ f32x4 mfma16(bf16x8 a, bf16x8 b, f32x4 c) {
    return __builtin_amdgcn_mfma_f32_16x16x32_bf16(a, b, c, 0, 0, 0);
}

// ---------------- K0 ----------------
__global__ __launch_bounds__(256) void k_split_bf16(const float* __restrict__ in,
                                                    unsigned short* __restrict__ hi,
                                                    unsigned short* __restrict__ lo, int n) {
    int i = blockIdx.x * 256 + threadIdx.x;
    if (i < n) {
        float f = in[i];
        unsigned short h = f2bf(f);
        hi[i] = h;
        lo[i] = f2bf(f - bf2f(h));
    }
}

__global__ __launch_bounds__(256) void build_wcat(const float* __restrict__ Wq,
                                                  const float* __restrict__ Wk,
                                                  const float* __restrict__ Wv,
                                                  const float* __restrict__ Wog,
                                                  unsigned short* __restrict__ wh,
                                                  unsigned short* __restrict__ wl) {
    int idx = blockIdx.x * 256 + threadIdx.x;
    if (idx >= 2304 * 1024) return;
    int row = idx >> 10, col = idx & 1023;
    float v;
    if (row < 1024)      v = Wq[(size_t)row * 1024 + col] * 0.08838834764831845f;
    else if (row < 1152) v = Wk[(size_t)(row - 1024) * 1024 + col];
    else if (row < 1280) v = Wv[(size_t)(row - 1152) * 1024 + col];
    else                 v = Wog[(size_t)(row - 1280) * 1024 + col];
    unsigned short h = f2bf(v);
    wh[idx] = h;
    wl[idx] = f2bf(v - bf2f(h));
}

// ---------------- K1: gates ----------------
__global__ __launch_bounds__(256) void gates_kernel(const float* __restrict__ x,
                                                    const float* __restrict__ Wi,
                                                    const float* __restrict__ bi,
                                                    const float* __restrict__ Wf,
                                                    const float* __restrict__ bfb,
                                                    float* __restrict__ ipre,
                                                    float* __restrict__ lgf) {
    int bs = blockIdx.x;
    int b = bs >> 11, s = bs & 2047;
    const float* xr = x + (size_t)bs * 1024;
    int lane = threadIdx.x & 63, w = threadIdx.x >> 6;
    const float* W = (w < 2) ? Wi : Wf;
    int h0 = (w & 1) * 4;
    float dot0 = 0.f, dot1 = 0.f, dot2 = 0.f, dot3 = 0.f;
    for (int i = lane; i < 1024; i += 64) {
        float xv = xr[i];
        dot0 += xv * W[(size_t)(h0 + 0) * 1024 + i];
        dot1 += xv * W[(size_t)(h0 + 1) * 1024 + i];
        dot2 += xv * W[(size_t)(h0 + 2) * 1024 + i];
        dot3 += xv * W[(size_t)(h0 + 3) * 1024 + i];
    }
#pragma unroll
    for (int o = 32; o; o >>= 1) {
        dot0 += __shfl_xor(dot0, o);
        dot1 += __shfl_xor(dot1, o);
        dot2 += __shfl_xor(dot2, o);
        dot3 += __shfl_xor(dot3, o);
    }
    if (lane == 0) {
        float d[4] = {dot0, dot1, dot2, dot3};
#pragma unroll
        for (int j = 0; j < 4; j++) {
            int hh = h0 + j;
            if (w < 2) {
                float z = d[j] + bi[hh];
                z = 15.f * tanhf(z * (1.f / 15.f));
                ipre[((size_t)b * 8 + hh) * 2048 + s] = z;
            } else {
                float z = d[j] + bfb[hh];
                z = 15.f * tanhf(z * (1.f / 15.f));
                lgf[((size_t)b * 8 + hh) * 2048 + s] = fminf(z, 0.f) - log1pf(expf(-fabsf(z)));
            }
        }
    }
}

// ---------------- K2: scan ----------------
__global__ void scan_kernel(const float* __restrict__ ipre, const float* __restrict__ lgf,
                            float* __restrict__ csum, float* __restrict__ aarr,
                            float* __restrict__ marr) {
    int bh = blockIdx.x;
    int lane = threadIdx.x;
    const float* lf = lgf + (size_t)bh * 2048;
    const float* ip = ipre + (size_t)bh * 2048;
    float* cs = csum + (size_t)bh * 2048;
    float* aa = aarr + (size_t)bh * 2048;
    float* mm = marr + (size_t)bh * 2048;
    float carry = 0.f;
    float carrym = -1e30f;
    for (int c = 0; c < 32; c++) {
        float v = lf[c * 64 + lane];
#pragma unroll
        for (int o = 1; o < 64; o <<= 1) {
            float t = __shfl_up(v, o);
            if (lane >= o) v += t;
        }
        float cval = carry + v;
        cs[c * 64 + lane] = cval;
        float a = ip[c * 64 + lane] - cval;
        aa[c * 64 + lane] = a;
        float mv = a;
#pragma unroll
        for (int o = 1; o < 64; o <<= 1) {
            float t = __shfl_up(mv, o);
            if (lane >= o) mv = fmaxf(mv, t);
        }
        float mval = fmaxf(carrym, mv);
        mm[c * 64 + lane] = mval;
        carry = __shfl(cval, 63);
        carrym = __shfl(mval, 63);
    }
}

// ---- K3/K6: 3-product GEMM, 128x128 tile ----
__global__ __launch_bounds__(256) void gemm_bt3(const unsigned short* __restrict__ Ah,
                                                const unsigned short* __restrict__ Al,
                                                const unsigned short* __restrict__ Bh,
                                                const unsigned short* __restrict__ Bl,
                                                void* __restrict__ Cp,
                                                unsigned short* __restrict__ Clo,
                                                int K, int ldc, int c_bf16) {
    __shared__ __attribute__((aligned(16))) unsigned short Ash[128 * 40];
    __shared__ __attribute__((aligned(16))) unsigned short Asl[128 * 40];
    __shared__ __attribute__((aligned(16))) unsigned short Bsh[128 * 40];
    __shared__ __attribute__((aligned(16))) unsigned short Bsl[128 * 40];
    const int tid = threadIdx.x;
    const int lane = tid & 63, wv = tid >> 6;
    const int wr = wv >> 1, wc = wv & 1;
    const int fr = lane & 15, fg = lane >> 4;
    const int srow = tid >> 1, scol = (tid & 1) * 16;
    const size_t aoff = (size_t)(blockIdx.x * 128 + srow) * K + scol;
    const size_t boff = (size_t)(blockIdx.y * 128 + srow) * K + scol;
    f32x4 acc[4][4] = {};
    for (int kt = 0; kt < K; kt += 32) {
        us8 avh0 = *(const us8*)(Ah + aoff + kt);
        us8 avh1 = *(const us8*)(Ah + aoff + kt + 8);
        us8 avl0 = *(const us8*)(Al + aoff + kt);
        us8 avl1 = *(const us8*)(Al + aoff + kt + 8);
        us8 bvh0 = *(const us8*)(Bh + boff + kt);
        us8 bvh1 = *(const us8*)(Bh + boff + kt + 8);
        us8 bvl0 = *(const us8*)(Bl + boff + kt);
        us8 bvl1 = *(const us8*)(Bl + boff + kt + 8);
        __syncthreads();
        *(us8*)&Ash[srow * 40 + scol] = avh0;
        *(us8*)&Ash[srow * 40 + scol + 8] = avh1;
        *(us8*)&Asl[srow * 40 + scol] = avl0;
        *(us8*)&Asl[srow * 40 + scol + 8] = avl1;
        *(us8*)&Bsh[srow * 40 + scol] = bvh0;
        *(us8*)&Bsh[srow * 40 + scol + 8] = bvh1;
        *(us8*)&Bsl[srow * 40 + scol] = bvl0;
        *(us8*)&Bsl[srow * 40 + scol + 8] = bvl1;
        __syncthreads();
        bf16x8 bfh[4], bfl[4];
#pragma unroll
        for (int j = 0; j < 4; j++) {
            bfh[j] = __builtin_bit_cast(bf16x8, *(const us8*)&Bsh[(64 * wc + 16 * j + fr) * 40 + fg * 8]);
            bfl[j] = __builtin_bit_cast(bf16x8, *(const us8*)&Bsl[(64 * wc + 16 * j + fr) * 40 + fg * 8]);
        }
        __builtin_amdgcn_s_setprio(1);
#pragma unroll
        for (int i = 0; i < 4; i++) {
            bf16x8 afh = __builtin_bit_cast(bf16x8, *(const us8*)&Ash[(64 * wr + 16 * i + fr) * 40 + fg * 8]);
            bf16x8 afl = __builtin_bit_cast(bf16x8, *(const us8*)&Asl[(64 * wr + 16 * i + fr) * 40 + fg * 8]);
#pragma unroll
            for (int j = 0; j < 4; j++) {
                acc[i][j] = mfma16(afh, bfh[j], acc[i][j]);
                acc[i][j] = mfma16(afh, bfl[j], acc[i][j]);
                acc[i][j] = mfma16(afl, bfh[j], acc[i][j]);
            }
        }
        __builtin_amdgcn_s_setprio(0);
    }
#pragma unroll
    for (int i = 0; i < 4; i++)
#pragma unroll
        for (int j = 0; j < 4; j++)
#pragma unroll
            for (int e = 0; e < 4; e++) {
                int r = blockIdx.x * 128 + 64 * wr + 16 * i + fg * 4 + e;
                int c = blockIdx.y * 128 + 64 * wc + 16 * j + fr;
                float v = acc[i][j][e];
                if (c_bf16) {
                    unsigned short h = f2bf(v);
                    ((unsigned short*)Cp)[(size_t)r * ldc + c] = h;
                    Clo[(size_t)r * ldc + c] = f2bf(v - bf2f(h));
                } else {
                    ((float*)Cp)[(size_t)r * ldc + c] = v;
                }
            }
}

// ---------------- K4: vT via coalesced LDS-tiled transpose ----------------
__global__ __launch_bounds__(256) void make_vt(const unsigned short* __restrict__ ph,
                                               const unsigned short* __restrict__ pl,
                                               unsigned short* __restrict__ vTh,
                                               unsigned short* __restrict__ vTl) {
    __shared__ __attribute__((aligned(16))) unsigned short th[64 * 68];
    __shared__ __attribute__((aligned(16))) unsigned short tl[64 * 68];
    // 128 blocks = b(2) x ct(2) x st(32): 64 ch x 64 s tile
    const int bid = blockIdx.x;
    const int st = bid & 31, ct = (bid >> 5) & 1, b = bid >> 6;
    const int tid = threadIdx.x;
    {
        const int sr = tid >> 2, cc = (tid & 3) * 16;
        const size_t rbase = (size_t)(b * 2048 + st * 64 + sr) * 2304 + 1152 + ct * 64 + cc;
        us8 a0 = *(const us8*)(ph + rbase);
        us8 a1 = *(const us8*)(ph + rbase + 8);
        us8 c0 = *(const us8*)(pl + rbase);
        us8 c1 = *(const us8*)(pl + rbase + 8);
        *(us8*)&th[sr * 68 + cc] = a0;
        *(us8*)&th[sr * 68 + cc + 8] = a1;
        *(us8*)&tl[sr * 68 + cc] = c0;
        *(us8*)&tl[sr * 68 + cc + 8] = c1;
    }
    __syncthreads();
    {
        const int cr = tid >> 2, ss = (tid & 3) * 16;
        us8 oh0, oh1, ol0, ol1;
#pragma unroll
        for (int e = 0; e < 8; e++) {
            oh0[e] = th[(ss + e) * 68 + cr];
            oh1[e] = th[(ss + 8 + e) * 68 + cr];
            ol0[e] = tl[(ss + e) * 68 + cr];
            ol1[e] = tl[(ss + 8 + e) * 68 + cr];
        }
        const size_t wbase = (size_t)b * 128 * 2048 + (size_t)(ct * 64 + cr) * 2048 + st * 64 + ss;
        *(us8*)&vTh[wbase] = oh0;
        *(us8*)&vTh[wbase + 8] = oh1;
        *(us8*)&vTl[wbase] = ol0;
        *(us8*)&vTl[wbase + 8] = ol1;
    }
}

// ---------------- K5: fused attn — dbuf LDS, S^T QK (3-acc), reg-P, MFMA PV --
__global__ __launch_bounds__(256, 2) void attn_fused(const unsigned short* __restrict__ projh,
                                                     const unsigned short* __restrict__ projl,
                                                     const unsigned short* __restrict__ vTh,
                                                     const unsigned short* __restrict__ vTl,
                                                     const float* __restrict__ aarr,
                                                     const float* __restrict__ marr,
                                                     const float* __restrict__ csum,
                                                     const float* __restrict__ lnw,
                                                     unsigned short* __restrict__ ho_hi,
                                                     unsigned short* __restrict__ ho_lo) {
    __shared__ __attribute__((aligned(16))) unsigned short Klh[2][32 * 148];
    __shared__ __attribute__((aligned(16))) unsigned short Kll[2][32 * 148];
    __shared__ __attribute__((aligned(16))) unsigned short Vlh[2][128 * 40];
    __shared__ __attribute__((aligned(16))) unsigned short Vll[2][128 * 40];
    __shared__ float al[2][32];

    // 512 blocks; (i, i+256) -> (bh,qt),(bh,31-qt) complementary pairing
    const int idx = blockIdx.x;
    const int half = idx >> 8;
    const int pid = idx & 255;
    const int bh = pid & 15;
    const int qt0 = pid >> 4;
    const int qt = half ? (31 - qt0) : qt0;
    const int b = bh >> 3, h = bh & 7;
    const int tid = threadIdx.x, lane = tid & 63, w = tid >> 6;
    const int fr = lane & 15, fg = lane >> 4;
    const int q0 = qt * 64;
    const int qg = q0 + 16 * w + fr;          // this lane's q row

    // Q fragments hi/lo (B-operand layout, col=fr)
    bf16x8 qfh[4], qfl[4];
    {
        const size_t qoff = (size_t)(b * 2048 + qg) * 2304 + h * 128;
#pragma unroll
        for (int ks = 0; ks < 4; ks++) {
            qfh[ks] = __builtin_bit_cast(bf16x8, *(const us8*)(projh + qoff + ks * 32 + fg * 8));
            qfl[ks] = __builtin_bit_cast(bf16x8, *(const us8*)(projl + qoff + ks * 32 + fg * 8));
        }
    }
    const float ma_q = marr[(size_t)bh * 2048 + qg];

    f32x4 acc[8] = {};
    float b_run = 0.f;

    const int kr = tid >> 3, kc = (tid & 7) * 16;   // K staging
    const int vr = tid >> 1, vc = (tid & 1) * 16;   // V^T staging: row=ch, col=key
    const size_t kbase = (size_t)(b * 2048) * 2304 + 1024;
    const size_t vtbase = (size_t)b * 128 * 2048;

    const int nt = 2 * qt + 2;
    us8 kh0, kh1, kl0, kl1, vh0, vh1, vl0, vl1;
    float a_st;
#define LOADT(T0)                                                              \
    {                                                                          \
        const size_t ko = kbase + (size_t)((T0) + kr) * 2304 + kc;             \
        const size_t vo = vtbase + (size_t)vr * 2048 + (T0) + vc;              \
        kh0 = *(const us8*)(projh + ko);                                       \
        kh1 = *(const us8*)(projh + ko + 8);                                   \
        kl0 = *(const us8*)(projl + ko);                                       \
        kl1 = *(const us8*)(projl + ko + 8);                                   \
        vh0 = *(const us8*)(vTh + vo);                                         \
        vh1 = *(const us8*)(vTh + vo + 8);                                     \
        vl0 = *(const us8*)(vTl + vo);                                         \
        vl1 = *(const us8*)(vTl + vo + 8);                                     \
        a_st = (tid < 32) ? aarr[(size_t)bh * 2048 + (T0) + tid] : 0.f;        \
    }
#define STORET(BUF)                                                            \
    {                                                                          \
        *(us8*)&Klh[BUF][kr * 148 + kc] = kh0;                                 \
        *(us8*)&Klh[BUF][kr * 148 + kc + 8] = kh1;                             \
        *(us8*)&Kll[BUF][kr * 148 + kc] = kl0;                                 \
        *(us8*)&Kll[BUF][kr * 148 + kc + 8] = kl1;                             \
        *(us8*)&Vlh[BUF][vr * 40 + vc] = vh0;                                  \
        *(us8*)&Vlh[BUF][vr * 40 + vc + 8] = vh1;                              \
        *(us8*)&Vll[BUF][vr * 40 + vc] = vl0;                                  \
        *(us8*)&Vll[BUF][vr * 40 + vc + 8] = vl1;                              \
        if (tid < 32) al[BUF][tid] = a_st;                                     \
    }

    // prologue: stage tile 0 into buf0, prefetch tile 1 into regs
    LOADT(0);
    STORET(0);
    if (nt > 1) LOADT(32);
    __syncthreads();

    for (int kt = 0; kt < nt; kt++) {
        const int cur = kt & 1;
        const int t0 = kt * 32;
        // write next tile (regs) to the other buffer; prefetch tile kt+2
        if (kt + 1 < nt) {
            STORET(cur ^ 1);
            if (kt + 2 < nt) LOADT((kt + 2) * 32);
        }

        // S^T = mfma(K, Q): D[key(row), q(col)]; 3 split accumulators for ILP
        float dj[2][4];
#pragma unroll
        for (int j = 0; j < 2; j++) {
            f32x4 sfa = {}, sfb = {}, sfc = {};
            __builtin_amdgcn_s_setprio(1);
#pragma unroll
            for (int ks = 0; ks < 4; ks++) {
                bf16x8 kfh = __builtin_bit_cast(bf16x8, *(const us8*)&Klh[cur][(j * 16 + fr) * 148 + ks * 32 + fg * 8]);
                bf16x8 kfl = __builtin_bit_cast(bf16x8, *(const us8*)&Kll[cur][(j * 16 + fr) * 148 + ks * 32 + fg * 8]);
                sfa = mfma16(kfh, qfh[ks], sfa);
                sfb = mfma16(kfh, qfl[ks], sfb);
                sfc = mfma16(kfl, qfh[ks], sfc);
            }
            __builtin_amdgcn_s_setprio(0);
            f32x4 sf = (sfa + sfb) + sfc;
#pragma unroll
            for (int r = 0; r < 4; r++) {
                const int kloc = j * 16 + fg * 4 + r;
                const int key = t0 + kloc;
                const float atv = al[cur][kloc];
                dj[j][r] = (key <= qg) ? sf[r] * __expf(atv - ma_q) : 0.f;
            }
        }

        // b_run: sum over the 32 keys for q=fr (replicated over fg)
        {
            float ts = dj[0][0] + dj[0][1] + dj[0][2] + dj[0][3]
                     + dj[1][0] + dj[1][1] + dj[1][2] + dj[1][3];
            ts += __shfl_xor(ts, 16);
            ts += __shfl_xor(ts, 32);
            b_run += ts;
        }

        // D-frag -> B-frag relayout (in-register): p8[e] = P[q=fr][k=8g+e]
        float p8[8];
        const int srlo = 32 * ((lane >> 4) & 1) + fr;
#pragma unroll
        for (int e = 0; e < 8; e++) {
            const int sl = srlo + ((e >= 4) ? 16 : 0);
            const float v0 = __shfl(dj[0][e & 3], sl);
            const float v1 = __shfl(dj[1][e & 3], sl);
            p8[e] = (lane & 32) ? v1 : v0;
        }
        us8 phu, plu;
#pragma unroll
        for (int e = 0; e < 8; e++) {
            unsigned short hh = f2bf(p8[e]);
            phu[e] = hh;
            plu[e] = f2bf(p8[e] - bf2f(hh));
        }
        const bf16x8 pfh = __builtin_bit_cast(bf16x8, phu);
        const bf16x8 pfl = __builtin_bit_cast(bf16x8, plu);

        // PV: O^T[ch, q] += mfma(V^T, P), V^T from LDS
        __builtin_amdgcn_s_setprio(1);
#pragma unroll
        for (int jb = 0; jb < 8; jb++) {
            bf16x8 vfh = __builtin_bit_cast(bf16x8, *(const us8*)&Vlh[cur][(jb * 16 + fr) * 40 + fg * 8]);
            bf16x8 vfl = __builtin_bit_cast(bf16x8, *(const us8*)&Vll[cur][(jb * 16 + fr) * 40 + fg * 8]);
            acc[jb] = mfma16(vfh, pfh, acc[jb]);
            acc[jb] = mfma16(vfh, pfl, acc[jb]);
            acc[jb] = mfma16(vfl, pfh, acc[jb]);
        }
        __builtin_amdgcn_s_setprio(0);
        __syncthreads();
    }
#undef LOADT
#undef STORET

    // finalize: per-lane q=fr, 32 channels ch = jb*16 + fg*4 + r
    const float cs_q = csum[(size_t)bh * 2048 + qg];
    const float nf = __expf(-(cs_q + ma_q));
    const float n = fmaxf(fabsf(b_run), nf);
    const float inv = 1.f / (n + 1e-6f);
#pragma unroll
    for (int jb = 0; jb < 8; jb++) acc[jb] *= inv;

    float s1 = 0.f;
#pragma unroll
    for (int jb = 0; jb < 8; jb++) s1 += acc[jb][0] + acc[jb][1] + acc[jb][2] + acc[jb][3];
    s1 += __shfl_xor(s1, 16);
    s1 += __shfl_xor(s1, 32);
    const float mu = s1 * (1.f / 128.f);
    float vv = 0.f;
#pragma unroll
    for (int jb = 0; jb < 8; jb++)
#pragma unroll
        for (int e = 0; e < 4; e++) {
            float d = acc[jb][e] - mu;
            vv += d * d;
        }
    vv += __shfl_xor(vv, 16);
    vv += __shfl_xor(vv, 32);
    const float rstd = rsqrtf(vv * (1.f / 128.f) + 1e-6f);

    const size_t obase = (size_t)(b * 2048 + qg) * 2304 + 1280 + h * 128 + fg * 4;
    const size_t hbase = (size_t)(b * 2048 + qg) * 1024 + h * 128 + fg * 4;
#pragma unroll
    for (int jb = 0; jb < 8; jb++) {
        us4 ogh = *(const us4*)(projh + obase + jb * 16);
        us4 ogl = *(const us4*)(projl + obase + jb * 16);
        f32x4 lw = *(const f32x4*)&lnw[h * 128 + jb * 16 + fg * 4];
        us4 hi4, lo4;
#pragma unroll
        for (int e = 0; e < 4; e++) {
            const float og = bf2f(ogh[e]) + bf2f(ogl[e]);
            const float sig = 1.f / (1.f + __expf(-og));
            const float ho = (acc[jb][e] - mu) * rstd * lw[e] * sig;
            unsigned short h1 = f2bf(ho);
            hi4[e] = h1;
            lo4[e] = f2bf(ho - bf2f(h1));
        }
        *(us4*)&ho_hi[hbase + jb * 16] = hi4;
        *(us4*)&ho_lo[hbase + jb * 16] = lo4;
    }
}

// ---------------------------------------------------------------------------
extern "C" void kernel_launch(void* const* d_in, const int* in_sizes, int n_in,
                              void* d_out, int out_size, void* d_ws, size_t ws_size,
                              hipStream_t stream) {
    (void)in_sizes; (void)n_in; (void)out_size; (void)ws_size;
    const float* x    = (const float*)d_in[0];
    const float* Wq   = (const float*)d_in[1];
    const float* Wk   = (const float*)d_in[2];
    const float* Wv   = (const float*)d_in[3];
    const float* Wog  = (const float*)d_in[4];
    const float* Wi   = (const float*)d_in[5];
    const float* bi   = (const float*)d_in[6];
    const float* Wf   = (const float*)d_in[7];
    const float* bfb  = (const float*)d_in[8];
    const float* lnw  = (const float*)d_in[9];
    const float* Wout = (const float*)d_in[10];

    char* p = (char*)d_ws;
    auto carve = [&](size_t bytes) -> char* {
        char* r = p;
        p += (bytes + 255) & ~(size_t)255;
        return r;
    };
    unsigned short* x_hi   = (unsigned short*)carve(4194304ull * 2);
    unsigned short* x_lo   = (unsigned short*)carve(4194304ull * 2);
    unsigned short* wc_hi  = (unsigned short*)carve(2359296ull * 2);
    unsigned short* wc_lo  = (unsigned short*)carve(2359296ull * 2);
    unsigned short* wo_hi  = (unsigned short*)carve(1048576ull * 2);
    unsigned short* wo_lo  = (unsigned short*)carve(1048576ull * 2);
    unsigned short* pr_hi  = (unsigned short*)carve(4096ull * 2304 * 2);
    unsigned short* pr_lo  = (unsigned short*)carve(4096ull * 2304 * 2);
    unsigned short* vT_hi  = (unsigned short*)carve(524288ull * 2);
    unsigned short* vT_lo  = (unsigned short*)carve(524288ull * 2);
    float* ipre    = (float*)carve(32768ull * 4);
    float* lgf_buf = (float*)carve(32768ull * 4);
    float* csum    = (float*)carve(32768ull * 4);
    float* aarr    = (float*)carve(32768ull * 4);
    float* marr    = (float*)carve(32768ull * 4);
    unsigned short* ho_hi = x_hi;   // x dead after proj GEMM
    unsigned short* ho_lo = x_lo;

    k_split_bf16<<<16384, 256, 0, stream>>>(x, x_hi, x_lo, 4194304);
    build_wcat<<<(2359296 + 255) / 256, 256, 0, stream>>>(Wq, Wk, Wv, Wog, wc_hi, wc_lo);
    k_split_bf16<<<4096, 256, 0, stream>>>(Wout, wo_hi, wo_lo, 1048576);
    gates_kernel<<<4096, 256, 0, stream>>>(x, Wi, bi, Wf, bfb, ipre, lgf_buf);
    scan_kernel<<<16, 64, 0, stream>>>(ipre, lgf_buf, csum, aarr, marr);
    gemm_bt3<<<dim3(32, 18), 256, 0, stream>>>(x_hi, x_lo, wc_hi, wc_lo, pr_hi, pr_lo, 1024, 2304, 1);
    make_vt<<<128, 256, 0, stream>>>(pr_hi, pr_lo, vT_hi, vT_lo);
    attn_fused<<<512, 256, 0, stream>>>(pr_hi, pr_lo, vT_hi, vT_lo, aarr, marr, csum, lnw, ho_hi, ho_lo);
    gemm_bt3<<<dim3(32, 8), 256, 0, stream>>>(ho_hi, ho_lo, wo_hi, wo_lo, d_out, nullptr, 1024, 1024, 0);
}